// Round 3
// baseline (1103.523 us; speedup 1.0000x reference)
//
#include <hip/hip_runtime.h>

#define N_NODES 100000
#define N_EDGES 1600000
#define ET (N_EDGES + N_NODES)
#define NEG_SLOPE 0.2f

typedef unsigned short u16;
typedef unsigned int u32;

__device__ __forceinline__ float bf2f(u16 v) {
    return __uint_as_float(((u32)v) << 16);
}
__device__ __forceinline__ u16 f2bf(float f) {
    u32 u = __float_as_uint(f);
    u32 r = (u + 0x7FFFu + ((u >> 16) & 1u)) >> 16;  // RNE
    return (u16)r;
}
// monotonic float<->uint encoding so atomicMax(uint) == float max
__device__ __forceinline__ u32 enc_f(float f) {
    u32 u = __float_as_uint(f);
    return (u & 0x80000000u) ? ~u : (u | 0x80000000u);
}
__device__ __forceinline__ float dec_f(u32 e) {
    return __uint_as_float((e & 0x80000000u) ? (e ^ 0x80000000u) : ~e);
}
__device__ __forceinline__ float lrelu(float x) { return x > 0.f ? x : NEG_SLOPE * x; }
// load float from buffer that is either bf16 (bf=1) or f32 (bf=0) storage
__device__ __forceinline__ float ldf(const void* p, int i, int bf) {
    return bf ? bf2f(((const u16*)p)[i]) : ((const float*)p)[i];
}
__device__ __forceinline__ void get_edge(const int* __restrict__ ei, int e, int ei64,
                                         int& s, int& d) {
    if (e < N_EDGES) {
        if (ei64) { s = ei[2 * e]; d = ei[2 * (N_EDGES + e)]; }
        else      { s = ei[e];     d = ei[N_EDGES + e]; }
    } else { s = d = e - N_EDGES; }
}

// ---------------------------------------------------------------------------
// Detect input storage. flags[0]=1 iff float arrays are bf16-stored (expect 0),
// flags[1]=1 iff edge_index is int64-stored (expect 0).
// ---------------------------------------------------------------------------
__global__ void detect_kernel(const u32* __restrict__ x32, const int* __restrict__ ei,
                              int* __restrict__ flags) {
    if (blockIdx.x != 0 || threadIdx.x != 0) return;
    int cnt = 0;
    for (int i = 0; i < 64; ++i) {
        u32 e = (x32[i] >> 7) & 0xFFu;   // bf16 storage: low-half bf16 exponent
        if (e >= 96u && e <= 143u) cnt++;
    }
    flags[0] = (cnt >= 48) ? 1 : 0;
    int nz = 0;
    for (int i = 0; i < 128; ++i) nz += (ei[2 * i + 1] != 0);  // int64: high words zero
    flags[1] = (nz == 0) ? 1 : 0;
}

// ---------------------------------------------------------------------------
// GEMM1: h[N,64](bf16) = x[N,128] @ W[128,64]; as_[n], ad_[n] score dots.
// 32 nodes/block, 256 threads, thread = 2 nodes x 4 channels.
// ---------------------------------------------------------------------------
__global__ __launch_bounds__(256) void gemm1_kernel(
    const u32* __restrict__ x32, const u32* __restrict__ W32,
    const void* __restrict__ a_src, const void* __restrict__ a_dst,
    const int* __restrict__ flags,
    u16* __restrict__ h, float* __restrict__ as_, float* __restrict__ ad_)
{
    __shared__ __align__(16) float Wl[128 * 64];   // 32 KB
    __shared__ __align__(16) float xs[32 * 132];   // 16.5 KB
    const int tid = threadIdx.x;
    const int node0 = blockIdx.x * 32;
    const int bf = flags[0];

    if (bf) {
        for (int i = tid; i < 4096; i += 256) {
            u32 u = W32[i];
            *(float2*)&Wl[2 * i] = make_float2(__uint_as_float(u << 16),
                                               __uint_as_float(u & 0xFFFF0000u));
        }
        for (int i = tid; i < 2048; i += 256) {
            int nl = i >> 6, kk = i & 63;
            int n = node0 + nl;
            u32 u = (n < N_NODES) ? x32[(size_t)n * 64 + kk] : 0u;
            *(float2*)&xs[nl * 132 + 2 * kk] = make_float2(__uint_as_float(u << 16),
                                                           __uint_as_float(u & 0xFFFF0000u));
        }
    } else {
        for (int i = tid; i < 8192; i += 256) Wl[i] = __uint_as_float(W32[i]);
        for (int i = tid; i < 4096; i += 256) {
            int nl = i >> 7, kk = i & 127;
            int n = node0 + nl;
            xs[nl * 132 + kk] = (n < N_NODES) ? __uint_as_float(x32[(size_t)n * 128 + kk]) : 0.f;
        }
    }
    __syncthreads();

    const int ch0 = (tid & 15) * 4;
    const int n0 = (tid >> 4) * 2;

    float acc0[4] = {0.f, 0.f, 0.f, 0.f}, acc1[4] = {0.f, 0.f, 0.f, 0.f};
    for (int k = 0; k < 128; k += 4) {
        float4 xa = *(const float4*)&xs[n0 * 132 + k];
        float4 xb = *(const float4*)&xs[(n0 + 1) * 132 + k];
        const float* xap = (const float*)&xa;
        const float* xbp = (const float*)&xb;
        #pragma unroll
        for (int kk = 0; kk < 4; ++kk) {
            float4 w = *(const float4*)&Wl[(k + kk) * 64 + ch0];
            float va = xap[kk], vb = xbp[kk];
            acc0[0] += va * w.x; acc0[1] += va * w.y; acc0[2] += va * w.z; acc0[3] += va * w.w;
            acc1[0] += vb * w.x; acc1[1] += vb * w.y; acc1[2] += vb * w.z; acc1[3] += vb * w.w;
        }
    }
    float ps0 = 0.f, ps1 = 0.f, pd0 = 0.f, pd1 = 0.f;
    #pragma unroll
    for (int q = 0; q < 4; ++q) {
        float asv = ldf(a_src, ch0 + q, bf);
        float adv = ldf(a_dst, ch0 + q, bf);
        ps0 += acc0[q] * asv; pd0 += acc0[q] * adv;
        ps1 += acc1[q] * asv; pd1 += acc1[q] * adv;
    }
    #pragma unroll
    for (int off = 1; off < 16; off <<= 1) {
        ps0 += __shfl_xor(ps0, off);
        pd0 += __shfl_xor(pd0, off);
        ps1 += __shfl_xor(ps1, off);
        pd1 += __shfl_xor(pd1, off);
    }
    int na = node0 + n0, nb = na + 1;
    if (na < N_NODES) {
        u32 p0 = (u32)f2bf(acc0[0]) | ((u32)f2bf(acc0[1]) << 16);
        u32 p1 = (u32)f2bf(acc0[2]) | ((u32)f2bf(acc0[3]) << 16);
        *(uint2*)&h[(size_t)na * 64 + ch0] = make_uint2(p0, p1);
        if ((tid & 15) == 0) { as_[na] = ps0; ad_[na] = pd0; }
    }
    if (nb < N_NODES) {
        u32 p0 = (u32)f2bf(acc1[0]) | ((u32)f2bf(acc1[1]) << 16);
        u32 p1 = (u32)f2bf(acc1[2]) | ((u32)f2bf(acc1[3]) << 16);
        *(uint2*)&h[(size_t)nb * 64 + ch0] = make_uint2(p0, p1);
        if ((tid & 15) == 0) { as_[nb] = ps1; ad_[nb] = pd1; }
    }
}

// ---------------------------------------------------------------------------
// GEMM2: hin = relu(agg1 + b1); h2[N,32](bf16) = hin[N,64] @ W[64,32]; alphas.
// ---------------------------------------------------------------------------
__global__ __launch_bounds__(256) void gemm2_kernel(
    const float* __restrict__ agg1, const void* __restrict__ b1,
    const u32* __restrict__ W32, const void* __restrict__ a_src,
    const void* __restrict__ a_dst, const int* __restrict__ flags,
    u16* __restrict__ h, float* __restrict__ as_, float* __restrict__ ad_)
{
    __shared__ __align__(16) float Wl[64 * 32];    // 8 KB
    __shared__ __align__(16) float xs[64 * 68];    // 17.4 KB
    const int tid = threadIdx.x;
    const int node0 = blockIdx.x * 64;
    const int bf = flags[0];

    if (bf) {
        for (int i = tid; i < 1024; i += 256) {
            u32 u = W32[i];
            *(float2*)&Wl[2 * i] = make_float2(__uint_as_float(u << 16),
                                               __uint_as_float(u & 0xFFFF0000u));
        }
    } else {
        for (int i = tid; i < 2048; i += 256) Wl[i] = __uint_as_float(W32[i]);
    }
    for (int i = tid; i < 64 * 64; i += 256) {
        int nl = i >> 6, k = i & 63;
        int n = node0 + nl;
        float v = 0.f;
        if (n < N_NODES) v = agg1[(size_t)n * 64 + k] + ldf(b1, k, bf);
        xs[nl * 68 + k] = fmaxf(v, 0.f);
    }
    __syncthreads();

    const int ch0 = (tid & 7) * 4;
    const int n0 = (tid >> 3) * 2;
    float acc0[4] = {0.f, 0.f, 0.f, 0.f}, acc1[4] = {0.f, 0.f, 0.f, 0.f};
    for (int k = 0; k < 64; k += 4) {
        float4 xa = *(const float4*)&xs[n0 * 68 + k];
        float4 xb = *(const float4*)&xs[(n0 + 1) * 68 + k];
        const float* xap = (const float*)&xa;
        const float* xbp = (const float*)&xb;
        #pragma unroll
        for (int kk = 0; kk < 4; ++kk) {
            float4 w = *(const float4*)&Wl[(k + kk) * 32 + ch0];
            float va = xap[kk], vb = xbp[kk];
            acc0[0] += va * w.x; acc0[1] += va * w.y; acc0[2] += va * w.z; acc0[3] += va * w.w;
            acc1[0] += vb * w.x; acc1[1] += vb * w.y; acc1[2] += vb * w.z; acc1[3] += vb * w.w;
        }
    }
    float ps0 = 0.f, ps1 = 0.f, pd0 = 0.f, pd1 = 0.f;
    #pragma unroll
    for (int q = 0; q < 4; ++q) {
        float asv = ldf(a_src, ch0 + q, bf);
        float adv = ldf(a_dst, ch0 + q, bf);
        ps0 += acc0[q] * asv; pd0 += acc0[q] * adv;
        ps1 += acc1[q] * asv; pd1 += acc1[q] * adv;
    }
    #pragma unroll
    for (int off = 1; off < 8; off <<= 1) {
        ps0 += __shfl_xor(ps0, off);
        pd0 += __shfl_xor(pd0, off);
        ps1 += __shfl_xor(ps1, off);
        pd1 += __shfl_xor(pd1, off);
    }
    int na = node0 + n0, nb = na + 1;
    if (na < N_NODES) {
        u32 p0 = (u32)f2bf(acc0[0]) | ((u32)f2bf(acc0[1]) << 16);
        u32 p1 = (u32)f2bf(acc0[2]) | ((u32)f2bf(acc0[3]) << 16);
        *(uint2*)&h[(size_t)na * 32 + ch0] = make_uint2(p0, p1);
        if ((tid & 7) == 0) { as_[na] = ps0; ad_[na] = pd0; }
    }
    if (nb < N_NODES) {
        u32 p0 = (u32)f2bf(acc1[0]) | ((u32)f2bf(acc1[1]) << 16);
        u32 p1 = (u32)f2bf(acc1[2]) | ((u32)f2bf(acc1[3]) << 16);
        *(uint2*)&h[(size_t)nb * 32 + ch0] = make_uint2(p0, p1);
        if ((tid & 7) == 0) { as_[nb] = ps1; ad_[nb] = pd1; }
    }
}

// ---------------------------------------------------------------------------
__global__ __launch_bounds__(256) void edge_max_kernel(
    const int* __restrict__ ei, const float* __restrict__ as_,
    const float* __restrict__ ad_, const int* __restrict__ flags,
    u32* __restrict__ menc)
{
    int e = blockIdx.x * 256 + threadIdx.x;
    if (e >= ET) return;
    int s, d;
    get_edge(ei, e, flags[1], s, d);
    float sc = lrelu(as_[s] + ad_[d]);
    atomicMax(&menc[d], enc_f(sc));
}

__global__ __launch_bounds__(256) void edge_sum_kernel(
    const int* __restrict__ ei, const float* __restrict__ as_,
    const float* __restrict__ ad_, const int* __restrict__ flags,
    const u32* __restrict__ menc, float* __restrict__ z)
{
    int e = blockIdx.x * 256 + threadIdx.x;
    if (e >= ET) return;
    int s, d;
    get_edge(ei, e, flags[1], s, d);
    float sc = lrelu(as_[s] + ad_[d]);
    atomicAdd(&z[d], __expf(sc - dec_f(menc[d])));
}

template<int C, int SHIFT>
__global__ __launch_bounds__(256) void edge_agg_kernel(
    const int* __restrict__ ei, const float* __restrict__ as_,
    const float* __restrict__ ad_, const int* __restrict__ flags,
    const u32* __restrict__ menc, const float* __restrict__ z,
    const u16* __restrict__ h, float* __restrict__ agg)
{
    int gt = blockIdx.x * 256 + threadIdx.x;
    int e = gt >> SHIFT;
    int c = gt & (C - 1);
    if (e >= ET) return;
    int s, d;
    get_edge(ei, e, flags[1], s, d);
    float sc = lrelu(as_[s] + ad_[d]);
    float coef = __expf(sc - dec_f(menc[d])) / z[d];
    atomicAdd(&agg[(size_t)d * C + c], coef * bf2f(h[(size_t)s * C + c]));
}

// Final: out = log_softmax(agg2 + b2) per row of 32, FLOAT32 store
__global__ __launch_bounds__(256) void lsm_kernel(
    const float* __restrict__ agg2, const void* __restrict__ b2,
    const int* __restrict__ flags, float* __restrict__ out)
{
    int gt = blockIdx.x * 256 + threadIdx.x;
    int n = gt >> 5, c = gt & 31;
    if (n >= N_NODES) return;
    float v = agg2[(size_t)n * 32 + c] + ldf(b2, c, flags[0]);
    float mx = v;
    #pragma unroll
    for (int off = 16; off > 0; off >>= 1) mx = fmaxf(mx, __shfl_xor(mx, off, 32));
    float ex = __expf(v - mx);
    float ss = ex;
    #pragma unroll
    for (int off = 16; off > 0; off >>= 1) ss += __shfl_xor(ss, off, 32);
    out[(size_t)n * 32 + c] = v - mx - __logf(ss);
}

// ---------------------------------------------------------------------------
extern "C" void kernel_launch(void* const* d_in, const int* in_sizes, int n_in,
                              void* d_out, int out_size, void* d_ws, size_t ws_size,
                              hipStream_t stream) {
    const u32* x32  = (const u32*)d_in[0];
    const int* ei   = (const int*)d_in[1];
    const u32* W1   = (const u32*)d_in[2];
    const void* a_s1 = d_in[3];
    const void* a_d1 = d_in[4];
    const void* b1   = d_in[5];
    const u32* W2   = (const u32*)d_in[6];
    const void* a_s2 = d_in[7];
    const void* a_d2 = d_in[8];
    const void* b2   = d_in[9];
    float* out = (float*)d_out;

    // workspace carve-up (~54.4 MB), all 16B aligned
    char* base = (char*)d_ws;
    int* flags = (int*)base;                       // 64 B
    u16* h     = (u16*)(base + 64);                // N*64 bf16, reused as N*32 in layer 2
    char* q = base + 64 + (size_t)N_NODES * 64 * 2;
    float* as1 = (float*)q; q += (size_t)N_NODES * 4;
    float* ad1 = (float*)q; q += (size_t)N_NODES * 4;
    float* as2 = (float*)q; q += (size_t)N_NODES * 4;
    float* ad2 = (float*)q; q += (size_t)N_NODES * 4;
    char* zero0 = q;
    float* agg1 = (float*)q; q += (size_t)N_NODES * 64 * 4;
    float* agg2 = (float*)q; q += (size_t)N_NODES * 32 * 4;
    float* z1   = (float*)q; q += (size_t)N_NODES * 4;
    u32*  menc1 = (u32*)q;  q += (size_t)N_NODES * 4;
    float* z2   = (float*)q; q += (size_t)N_NODES * 4;
    u32*  menc2 = (u32*)q;  q += (size_t)N_NODES * 4;
    hipMemsetAsync(zero0, 0, (size_t)(q - zero0), stream);

    const int eb = (ET + 255) / 256;

    detect_kernel<<<1, 64, 0, stream>>>(x32, ei, flags);

    // layer 1
    gemm1_kernel<<<(N_NODES + 31) / 32, 256, 0, stream>>>(x32, W1, a_s1, a_d1, flags, h, as1, ad1);
    edge_max_kernel<<<eb, 256, 0, stream>>>(ei, as1, ad1, flags, menc1);
    edge_sum_kernel<<<eb, 256, 0, stream>>>(ei, as1, ad1, flags, menc1, z1);
    edge_agg_kernel<64, 6><<<(int)(((size_t)ET * 64 + 255) / 256), 256, 0, stream>>>(
        ei, as1, ad1, flags, menc1, z1, h, agg1);

    // layer 2 (h reused as h2; relu+bias fused into gemm2 load)
    gemm2_kernel<<<(N_NODES + 63) / 64, 256, 0, stream>>>(agg1, b1, W2, a_s2, a_d2, flags, h, as2, ad2);
    edge_max_kernel<<<eb, 256, 0, stream>>>(ei, as2, ad2, flags, menc2);
    edge_sum_kernel<<<eb, 256, 0, stream>>>(ei, as2, ad2, flags, menc2, z2);
    edge_agg_kernel<32, 5><<<(int)(((size_t)ET * 32 + 255) / 256), 256, 0, stream>>>(
        ei, as2, ad2, flags, menc2, z2, h, agg2);

    // epilogue (float32 output)
    lsm_kernel<<<(N_NODES * 32 + 255) / 256, 256, 0, stream>>>(agg2, b2, flags, out);
}

// Round 4
// 623.388 us; speedup vs baseline: 1.7702x; 1.7702x over previous
//
#include <hip/hip_runtime.h>

#define N_NODES 100000
#define N_EDGES 1600000
#define ET (N_EDGES + N_NODES)
#define NEG_SLOPE 0.2f

typedef unsigned short u16;
typedef unsigned int u32;

__device__ __forceinline__ float bf2f(u16 v) {
    return __uint_as_float(((u32)v) << 16);
}
__device__ __forceinline__ u16 f2bf(float f) {
    u32 u = __float_as_uint(f);
    u32 r = (u + 0x7FFFu + ((u >> 16) & 1u)) >> 16;  // RNE
    return (u16)r;
}
__device__ __forceinline__ float lrelu(float x) { return x > 0.f ? x : NEG_SLOPE * x; }
__device__ __forceinline__ float ldf(const void* p, int i, int bf) {
    return bf ? bf2f(((const u16*)p)[i]) : ((const float*)p)[i];
}
__device__ __forceinline__ void get_edge(const int* __restrict__ ei, int e, int ei64,
                                         int& s, int& d) {
    if (e < N_EDGES) {
        if (ei64) { s = ei[2 * e]; d = ei[2 * (N_EDGES + e)]; }
        else      { s = ei[e];     d = ei[N_EDGES + e]; }
    } else { s = d = e - N_EDGES; }
}

// ---------------------------------------------------------------------------
// Detect input storage. flags[0]=1 iff float arrays bf16-stored (expect 0),
// flags[1]=1 iff edge_index int64-stored (expect 0).
// ---------------------------------------------------------------------------
__global__ void detect_kernel(const u32* __restrict__ x32, const int* __restrict__ ei,
                              int* __restrict__ flags) {
    if (blockIdx.x != 0 || threadIdx.x != 0) return;
    int cnt = 0;
    for (int i = 0; i < 64; ++i) {
        u32 e = (x32[i] >> 7) & 0xFFu;
        if (e >= 96u && e <= 143u) cnt++;
    }
    flags[0] = (cnt >= 48) ? 1 : 0;
    int nz = 0;
    for (int i = 0; i < 128; ++i) nz += (ei[2 * i + 1] != 0);
    flags[1] = (nz == 0) ? 1 : 0;
}

// ---------------------------------------------------------------------------
// CSR build: deg count -> 3-phase exclusive scan -> fill sorted src ids
// ---------------------------------------------------------------------------
__global__ __launch_bounds__(256) void count_kernel(
    const int* __restrict__ ei, const int* __restrict__ flags, int* __restrict__ deg)
{
    int e = blockIdx.x * 256 + threadIdx.x;
    if (e >= ET) return;
    int s, d;
    get_edge(ei, e, flags[1], s, d);
    atomicAdd(&deg[d], 1);
}

#define SCAN_NB ((N_NODES + 255) / 256)   // 391

__global__ __launch_bounds__(256) void scan1_kernel(
    const int* __restrict__ deg, int* __restrict__ rowptr, int* __restrict__ bsum)
{
    __shared__ int sd[256];
    int t = threadIdx.x;
    int i = blockIdx.x * 256 + t;
    int v = (i < N_NODES) ? deg[i] : 0;
    sd[t] = v;
    __syncthreads();
    for (int off = 1; off < 256; off <<= 1) {
        int x = (t >= off) ? sd[t - off] : 0;
        __syncthreads();
        sd[t] += x;
        __syncthreads();
    }
    if (i < N_NODES) rowptr[i] = sd[t] - v;   // exclusive within block
    if (t == 255) bsum[blockIdx.x] = sd[255];
}

__global__ __launch_bounds__(512) void scan2_kernel(int* __restrict__ bsum,
                                                    int* __restrict__ boff)
{
    __shared__ int sd[512];
    int t = threadIdx.x;
    int v = (t < SCAN_NB) ? bsum[t] : 0;
    sd[t] = v;
    __syncthreads();
    for (int off = 1; off < 512; off <<= 1) {
        int x = (t >= off) ? sd[t - off] : 0;
        __syncthreads();
        sd[t] += x;
        __syncthreads();
    }
    if (t < SCAN_NB) boff[t] = sd[t] - v;
}

__global__ __launch_bounds__(256) void scan3_kernel(
    int* __restrict__ rowptr, const int* __restrict__ boff, int* __restrict__ cursor)
{
    int i = blockIdx.x * 256 + threadIdx.x;
    if (i < N_NODES) {
        int r = rowptr[i] + boff[i >> 8];
        rowptr[i] = r;
        cursor[i] = r;
    }
    if (blockIdx.x == 0 && threadIdx.x == 0) rowptr[N_NODES] = ET;
}

__global__ __launch_bounds__(256) void fill_kernel(
    const int* __restrict__ ei, const int* __restrict__ flags,
    int* __restrict__ cursor, int* __restrict__ ssrc)
{
    int e = blockIdx.x * 256 + threadIdx.x;
    if (e >= ET) return;
    int s, d;
    get_edge(ei, e, flags[1], s, d);
    int pos = atomicAdd(&cursor[d], 1);
    ssrc[pos] = s;
}

// ---------------------------------------------------------------------------
// Fused per-dst GAT aggregation (online softmax, no atomics).
// One wave per dst node; 4 waves / block.
// Score phase: lane = edge (chunks of 64). Agg phase: lane = channel,
// h[src] reads are contiguous C*2 bytes (coalesced).
// ---------------------------------------------------------------------------
template<int C>
__global__ __launch_bounds__(256) void gat_agg_kernel(
    const int* __restrict__ rowptr, const int* __restrict__ ssrc,
    const float* __restrict__ as_, const float* __restrict__ ad_,
    const u16* __restrict__ h, float* __restrict__ agg)
{
    const int lane = threadIdx.x & 63;
    const int dst = blockIdx.x * 4 + (threadIdx.x >> 6);
    if (dst >= N_NODES) return;
    const int beg = rowptr[dst], end = rowptr[dst + 1];
    const float add = ad_[dst];
    const int ch = lane & (C - 1);

    float m = -1e30f, l = 0.f, acc = 0.f;
    for (int base = beg; base < end; base += 64) {
        int j = base + lane;
        int sj = 0;
        float sc = -1e30f;
        if (j < end) { sj = ssrc[j]; sc = lrelu(as_[sj] + add); }
        float cm = sc;
        #pragma unroll
        for (int off = 32; off > 0; off >>= 1) cm = fmaxf(cm, __shfl_xor(cm, off));
        float nm = fmaxf(m, cm);
        float scale = __expf(m - nm);
        float ex = (j < end) ? __expf(sc - nm) : 0.f;
        float cs = ex;
        #pragma unroll
        for (int off = 32; off > 0; off >>= 1) cs += __shfl_xor(cs, off);
        l = l * scale + cs;
        acc *= scale;
        m = nm;

        int cnt = min(64, end - base);
        if (C == 64) {
            for (int jj = 0; jj < cnt; ++jj) {
                float w = __shfl(ex, jj);
                int s = __shfl(sj, jj);
                acc = fmaf(w, bf2f(h[(size_t)s * 64 + lane]), acc);
            }
        } else {
            const int half = lane >> 5;   // two edges per iteration
            for (int jj = 0; jj < cnt; jj += 2) {
                int j2 = jj + half;
                float w = (j2 < cnt) ? __shfl(ex, j2) : 0.f;
                int s = __shfl(sj, min(j2, cnt - 1));
                acc = fmaf(w, bf2f(h[(size_t)s * C + ch]), acc);
            }
        }
    }
    if (C == 32) {
        acc += __shfl_xor(acc, 32);
        if (lane < 32) agg[(size_t)dst * C + ch] = acc / l;
    } else {
        agg[(size_t)dst * C + ch] = acc / l;
    }
}

// ---------------------------------------------------------------------------
// GEMM1: h[N,64](bf16) = x[N,128] @ W[128,64]; as_/ad_ score dots.
// ---------------------------------------------------------------------------
__global__ __launch_bounds__(256) void gemm1_kernel(
    const u32* __restrict__ x32, const u32* __restrict__ W32,
    const void* __restrict__ a_src, const void* __restrict__ a_dst,
    const int* __restrict__ flags,
    u16* __restrict__ h, float* __restrict__ as_, float* __restrict__ ad_)
{
    __shared__ __align__(16) float Wl[128 * 64];
    __shared__ __align__(16) float xs[32 * 132];
    const int tid = threadIdx.x;
    const int node0 = blockIdx.x * 32;
    const int bf = flags[0];

    if (bf) {
        for (int i = tid; i < 4096; i += 256) {
            u32 u = W32[i];
            *(float2*)&Wl[2 * i] = make_float2(__uint_as_float(u << 16),
                                               __uint_as_float(u & 0xFFFF0000u));
        }
        for (int i = tid; i < 2048; i += 256) {
            int nl = i >> 6, kk = i & 63;
            int n = node0 + nl;
            u32 u = (n < N_NODES) ? x32[(size_t)n * 64 + kk] : 0u;
            *(float2*)&xs[nl * 132 + 2 * kk] = make_float2(__uint_as_float(u << 16),
                                                           __uint_as_float(u & 0xFFFF0000u));
        }
    } else {
        for (int i = tid; i < 8192; i += 256) Wl[i] = __uint_as_float(W32[i]);
        for (int i = tid; i < 4096; i += 256) {
            int nl = i >> 7, kk = i & 127;
            int n = node0 + nl;
            xs[nl * 132 + kk] = (n < N_NODES) ? __uint_as_float(x32[(size_t)n * 128 + kk]) : 0.f;
        }
    }
    __syncthreads();

    const int ch0 = (tid & 15) * 4;
    const int n0 = (tid >> 4) * 2;

    float acc0[4] = {0.f, 0.f, 0.f, 0.f}, acc1[4] = {0.f, 0.f, 0.f, 0.f};
    for (int k = 0; k < 128; k += 4) {
        float4 xa = *(const float4*)&xs[n0 * 132 + k];
        float4 xb = *(const float4*)&xs[(n0 + 1) * 132 + k];
        const float* xap = (const float*)&xa;
        const float* xbp = (const float*)&xb;
        #pragma unroll
        for (int kk = 0; kk < 4; ++kk) {
            float4 w = *(const float4*)&Wl[(k + kk) * 64 + ch0];
            float va = xap[kk], vb = xbp[kk];
            acc0[0] += va * w.x; acc0[1] += va * w.y; acc0[2] += va * w.z; acc0[3] += va * w.w;
            acc1[0] += vb * w.x; acc1[1] += vb * w.y; acc1[2] += vb * w.z; acc1[3] += vb * w.w;
        }
    }
    float ps0 = 0.f, ps1 = 0.f, pd0 = 0.f, pd1 = 0.f;
    #pragma unroll
    for (int q = 0; q < 4; ++q) {
        float asv = ldf(a_src, ch0 + q, bf);
        float adv = ldf(a_dst, ch0 + q, bf);
        ps0 += acc0[q] * asv; pd0 += acc0[q] * adv;
        ps1 += acc1[q] * asv; pd1 += acc1[q] * adv;
    }
    #pragma unroll
    for (int off = 1; off < 16; off <<= 1) {
        ps0 += __shfl_xor(ps0, off);
        pd0 += __shfl_xor(pd0, off);
        ps1 += __shfl_xor(ps1, off);
        pd1 += __shfl_xor(pd1, off);
    }
    int na = node0 + n0, nb = na + 1;
    if (na < N_NODES) {
        u32 p0 = (u32)f2bf(acc0[0]) | ((u32)f2bf(acc0[1]) << 16);
        u32 p1 = (u32)f2bf(acc0[2]) | ((u32)f2bf(acc0[3]) << 16);
        *(uint2*)&h[(size_t)na * 64 + ch0] = make_uint2(p0, p1);
        if ((tid & 15) == 0) { as_[na] = ps0; ad_[na] = pd0; }
    }
    if (nb < N_NODES) {
        u32 p0 = (u32)f2bf(acc1[0]) | ((u32)f2bf(acc1[1]) << 16);
        u32 p1 = (u32)f2bf(acc1[2]) | ((u32)f2bf(acc1[3]) << 16);
        *(uint2*)&h[(size_t)nb * 64 + ch0] = make_uint2(p0, p1);
        if ((tid & 15) == 0) { as_[nb] = ps1; ad_[nb] = pd1; }
    }
}

// ---------------------------------------------------------------------------
// GEMM2: hin = relu(agg1 + b1); h2[N,32](bf16) = hin[N,64] @ W[64,32]; alphas.
// ---------------------------------------------------------------------------
__global__ __launch_bounds__(256) void gemm2_kernel(
    const float* __restrict__ agg1, const void* __restrict__ b1,
    const u32* __restrict__ W32, const void* __restrict__ a_src,
    const void* __restrict__ a_dst, const int* __restrict__ flags,
    u16* __restrict__ h, float* __restrict__ as_, float* __restrict__ ad_)
{
    __shared__ __align__(16) float Wl[64 * 32];
    __shared__ __align__(16) float xs[64 * 68];
    const int tid = threadIdx.x;
    const int node0 = blockIdx.x * 64;
    const int bf = flags[0];

    if (bf) {
        for (int i = tid; i < 1024; i += 256) {
            u32 u = W32[i];
            *(float2*)&Wl[2 * i] = make_float2(__uint_as_float(u << 16),
                                               __uint_as_float(u & 0xFFFF0000u));
        }
    } else {
        for (int i = tid; i < 2048; i += 256) Wl[i] = __uint_as_float(W32[i]);
    }
    for (int i = tid; i < 64 * 64; i += 256) {
        int nl = i >> 6, k = i & 63;
        int n = node0 + nl;
        float v = 0.f;
        if (n < N_NODES) v = agg1[(size_t)n * 64 + k] + ldf(b1, k, bf);
        xs[nl * 68 + k] = fmaxf(v, 0.f);
    }
    __syncthreads();

    const int ch0 = (tid & 7) * 4;
    const int n0 = (tid >> 3) * 2;
    float acc0[4] = {0.f, 0.f, 0.f, 0.f}, acc1[4] = {0.f, 0.f, 0.f, 0.f};
    for (int k = 0; k < 64; k += 4) {
        float4 xa = *(const float4*)&xs[n0 * 68 + k];
        float4 xb = *(const float4*)&xs[(n0 + 1) * 68 + k];
        const float* xap = (const float*)&xa;
        const float* xbp = (const float*)&xb;
        #pragma unroll
        for (int kk = 0; kk < 4; ++kk) {
            float4 w = *(const float4*)&Wl[(k + kk) * 32 + ch0];
            float va = xap[kk], vb = xbp[kk];
            acc0[0] += va * w.x; acc0[1] += va * w.y; acc0[2] += va * w.z; acc0[3] += va * w.w;
            acc1[0] += vb * w.x; acc1[1] += vb * w.y; acc1[2] += vb * w.z; acc1[3] += vb * w.w;
        }
    }
    float ps0 = 0.f, ps1 = 0.f, pd0 = 0.f, pd1 = 0.f;
    #pragma unroll
    for (int q = 0; q < 4; ++q) {
        float asv = ldf(a_src, ch0 + q, bf);
        float adv = ldf(a_dst, ch0 + q, bf);
        ps0 += acc0[q] * asv; pd0 += acc0[q] * adv;
        ps1 += acc1[q] * asv; pd1 += acc1[q] * adv;
    }
    #pragma unroll
    for (int off = 1; off < 8; off <<= 1) {
        ps0 += __shfl_xor(ps0, off);
        pd0 += __shfl_xor(pd0, off);
        ps1 += __shfl_xor(ps1, off);
        pd1 += __shfl_xor(pd1, off);
    }
    int na = node0 + n0, nb = na + 1;
    if (na < N_NODES) {
        u32 p0 = (u32)f2bf(acc0[0]) | ((u32)f2bf(acc0[1]) << 16);
        u32 p1 = (u32)f2bf(acc0[2]) | ((u32)f2bf(acc0[3]) << 16);
        *(uint2*)&h[(size_t)na * 32 + ch0] = make_uint2(p0, p1);
        if ((tid & 7) == 0) { as_[na] = ps0; ad_[na] = pd0; }
    }
    if (nb < N_NODES) {
        u32 p0 = (u32)f2bf(acc1[0]) | ((u32)f2bf(acc1[1]) << 16);
        u32 p1 = (u32)f2bf(acc1[2]) | ((u32)f2bf(acc1[3]) << 16);
        *(uint2*)&h[(size_t)nb * 32 + ch0] = make_uint2(p0, p1);
        if ((tid & 7) == 0) { as_[nb] = ps1; ad_[nb] = pd1; }
    }
}

// Final: out = log_softmax(agg2 + b2) per row of 32, float32 store
__global__ __launch_bounds__(256) void lsm_kernel(
    const float* __restrict__ agg2, const void* __restrict__ b2,
    const int* __restrict__ flags, float* __restrict__ out)
{
    int gt = blockIdx.x * 256 + threadIdx.x;
    int n = gt >> 5, c = gt & 31;
    if (n >= N_NODES) return;
    float v = agg2[(size_t)n * 32 + c] + ldf(b2, c, flags[0]);
    float mx = v;
    #pragma unroll
    for (int off = 16; off > 0; off >>= 1) mx = fmaxf(mx, __shfl_xor(mx, off, 32));
    float ex = __expf(v - mx);
    float ss = ex;
    #pragma unroll
    for (int off = 16; off > 0; off >>= 1) ss += __shfl_xor(ss, off, 32);
    out[(size_t)n * 32 + c] = v - mx - __logf(ss);
}

// ---------------------------------------------------------------------------
extern "C" void kernel_launch(void* const* d_in, const int* in_sizes, int n_in,
                              void* d_out, int out_size, void* d_ws, size_t ws_size,
                              hipStream_t stream) {
    const u32* x32  = (const u32*)d_in[0];
    const int* ei   = (const int*)d_in[1];
    const u32* W1   = (const u32*)d_in[2];
    const void* a_s1 = d_in[3];
    const void* a_d1 = d_in[4];
    const void* b1   = d_in[5];
    const u32* W2   = (const u32*)d_in[6];
    const void* a_s2 = d_in[7];
    const void* a_d2 = d_in[8];
    const void* b2   = d_in[9];
    float* out = (float*)d_out;

    // workspace carve-up (~61 MB), all 16B aligned
    char* base = (char*)d_ws;
    int* flags = (int*)base;
    u16* h     = (u16*)(base + 64);                           // N*64 bf16 (reused N*32)
    char* q = base + 64 + (size_t)N_NODES * 64 * 2;
    float* as1 = (float*)q; q += (size_t)N_NODES * 4;
    float* ad1 = (float*)q; q += (size_t)N_NODES * 4;
    float* as2 = (float*)q; q += (size_t)N_NODES * 4;
    float* ad2 = (float*)q; q += (size_t)N_NODES * 4;
    float* agg1 = (float*)q; q += (size_t)N_NODES * 64 * 4;
    float* agg2 = (float*)q; q += (size_t)N_NODES * 32 * 4;
    int* rowptr = (int*)q;  q += (size_t)(N_NODES + 16) * 4;
    int* cursor = (int*)q;  q += (size_t)N_NODES * 4;
    int* bsum   = (int*)q;  q += 2048;
    int* boff   = (int*)q;  q += 2048;
    int* ssrc   = (int*)q;  q += (size_t)ET * 4;
    char* deg0  = q;
    int* deg    = (int*)q;  q += (size_t)N_NODES * 4;
    hipMemsetAsync(deg0, 0, (size_t)N_NODES * 4, stream);     // only deg needs zeroing

    const int eb = (ET + 255) / 256;

    detect_kernel<<<1, 64, 0, stream>>>(x32, ei, flags);

    // CSR by dst (shared by both layers)
    count_kernel<<<eb, 256, 0, stream>>>(ei, flags, deg);
    scan1_kernel<<<SCAN_NB, 256, 0, stream>>>(deg, rowptr, bsum);
    scan2_kernel<<<1, 512, 0, stream>>>(bsum, boff);
    scan3_kernel<<<SCAN_NB, 256, 0, stream>>>(rowptr, boff, cursor);
    fill_kernel<<<eb, 256, 0, stream>>>(ei, flags, cursor, ssrc);

    // layer 1
    gemm1_kernel<<<(N_NODES + 31) / 32, 256, 0, stream>>>(x32, W1, a_s1, a_d1, flags, h, as1, ad1);
    gat_agg_kernel<64><<<(N_NODES + 3) / 4, 256, 0, stream>>>(rowptr, ssrc, as1, ad1, h, agg1);

    // layer 2
    gemm2_kernel<<<(N_NODES + 63) / 64, 256, 0, stream>>>(agg1, b1, W2, a_s2, a_d2, flags, h, as2, ad2);
    gat_agg_kernel<32><<<(N_NODES + 3) / 4, 256, 0, stream>>>(rowptr, ssrc, as2, ad2, h, agg2);

    // epilogue
    lsm_kernel<<<(N_NODES * 32 + 255) / 256, 256, 0, stream>>>(agg2, b2, flags, out);
}

// Round 5
// 506.800 us; speedup vs baseline: 2.1774x; 1.2300x over previous
//
#include <hip/hip_runtime.h>

#define N_NODES 100000
#define N_EDGES 1600000
#define ET (N_EDGES + N_NODES)
#define NEG_SLOPE 0.2f
#define NPART 8
#define PSIZE ((N_NODES + NPART - 1) / NPART)   // 12500
#define FCHUNK 2048

typedef unsigned short u16;
typedef unsigned int u32;

__device__ __forceinline__ float bf2f(u16 v) {
    return __uint_as_float(((u32)v) << 16);
}
__device__ __forceinline__ u16 f2bf(float f) {
    u32 u = __float_as_uint(f);
    u32 r = (u + 0x7FFFu + ((u >> 16) & 1u)) >> 16;  // RNE
    return (u16)r;
}
__device__ __forceinline__ float lrelu(float x) { return x > 0.f ? x : NEG_SLOPE * x; }
__device__ __forceinline__ float ldf(const void* p, int i, int bf) {
    return bf ? bf2f(((const u16*)p)[i]) : ((const float*)p)[i];
}
__device__ __forceinline__ int get_dst(const int* __restrict__ ei, int e, int ei64) {
    if (e < N_EDGES) return ei64 ? ei[2 * (N_EDGES + e)] : ei[N_EDGES + e];
    return e - N_EDGES;
}
__device__ __forceinline__ int get_src(const int* __restrict__ ei, int e, int ei64) {
    if (e < N_EDGES) return ei64 ? ei[2 * e] : ei[e];
    return e - N_EDGES;
}

// ---------------------------------------------------------------------------
// Detect input storage (parallel). flags[0]=1 iff floats bf16-stored,
// flags[1]=1 iff edge_index int64-stored.
// ---------------------------------------------------------------------------
__global__ void detect_kernel(const u32* __restrict__ x32, const int* __restrict__ ei,
                              int* __restrict__ flags) {
    int lane = threadIdx.x;  // 64
    u32 e = (x32[lane] >> 7) & 0xFFu;
    int ok = (e >= 96u && e <= 143u) ? 1 : 0;
    int cnt = (int)__popcll(__ballot(ok));
    int nz = (ei[2 * lane + 1] != 0) + (ei[2 * (lane + 64) + 1] != 0);
    #pragma unroll
    for (int off = 32; off > 0; off >>= 1) nz += __shfl_xor(nz, off);
    if (lane == 0) { flags[0] = (cnt >= 48) ? 1 : 0; flags[1] = (nz == 0) ? 1 : 0; }
}

// ---------------------------------------------------------------------------
// CSR build, XCD-partitioned: block b -> partition (b & 7) + edge chunk (b>>3).
// All blocks of a partition land on one XCD (round-robin heuristic), so the
// scatter window (deg/cursor 50 KB, ssrc 850 KB) stays in that XCD's L2.
// ---------------------------------------------------------------------------
__global__ __launch_bounds__(256) void count_kernel(
    const int* __restrict__ ei, const int* __restrict__ flags, int* __restrict__ deg)
{
    const int p = blockIdx.x & (NPART - 1);
    const int base = (blockIdx.x >> 3) * FCHUNK;
    const int lo = p * PSIZE, hi = min(lo + PSIZE, N_NODES);
    const int ei64 = flags[1];
    for (int i = threadIdx.x; i < FCHUNK; i += 256) {
        int e = base + i;
        if (e >= ET) break;
        int d = get_dst(ei, e, ei64);
        if (d >= lo && d < hi) atomicAdd(&deg[d], 1);
    }
}

#define SCAN_NB ((N_NODES + 255) / 256)   // 391

__global__ __launch_bounds__(256) void scan1_kernel(
    const int* __restrict__ deg, int* __restrict__ rowptr, int* __restrict__ bsum)
{
    __shared__ int sd[256];
    int t = threadIdx.x;
    int i = blockIdx.x * 256 + t;
    int v = (i < N_NODES) ? deg[i] : 0;
    sd[t] = v;
    __syncthreads();
    for (int off = 1; off < 256; off <<= 1) {
        int x = (t >= off) ? sd[t - off] : 0;
        __syncthreads();
        sd[t] += x;
        __syncthreads();
    }
    if (i < N_NODES) rowptr[i] = sd[t] - v;
    if (t == 255) bsum[blockIdx.x] = sd[255];
}

__global__ __launch_bounds__(512) void scan2_kernel(int* __restrict__ bsum,
                                                    int* __restrict__ boff)
{
    __shared__ int sd[512];
    int t = threadIdx.x;
    int v = (t < SCAN_NB) ? bsum[t] : 0;
    sd[t] = v;
    __syncthreads();
    for (int off = 1; off < 512; off <<= 1) {
        int x = (t >= off) ? sd[t - off] : 0;
        __syncthreads();
        sd[t] += x;
        __syncthreads();
    }
    if (t < SCAN_NB) boff[t] = sd[t] - v;
}

__global__ __launch_bounds__(256) void scan3_kernel(
    int* __restrict__ rowptr, const int* __restrict__ boff, int* __restrict__ cursor)
{
    int i = blockIdx.x * 256 + threadIdx.x;
    if (i < N_NODES) {
        int r = rowptr[i] + boff[i >> 8];
        rowptr[i] = r;
        cursor[i] = r;
    }
    if (blockIdx.x == 0 && threadIdx.x == 0) rowptr[N_NODES] = ET;
}

__global__ __launch_bounds__(256) void fill_kernel(
    const int* __restrict__ ei, const int* __restrict__ flags,
    int* __restrict__ cursor, int* __restrict__ ssrc)
{
    const int p = blockIdx.x & (NPART - 1);
    const int base = (blockIdx.x >> 3) * FCHUNK;
    const int lo = p * PSIZE, hi = min(lo + PSIZE, N_NODES);
    const int ei64 = flags[1];
    for (int i = threadIdx.x; i < FCHUNK; i += 256) {
        int e = base + i;
        if (e >= ET) break;
        int d = get_dst(ei, e, ei64);
        if (d >= lo && d < hi) {
            int s = get_src(ei, e, ei64);
            int pos = atomicAdd(&cursor[d], 1);
            ssrc[pos] = s;
        }
    }
}

// ---------------------------------------------------------------------------
// Fused per-dst GAT aggregation (online softmax, no atomics).
// One wave per dst; score phase lane=edge, agg phase lane=channel with
// 4 independent gathers in flight per iteration (latency hiding).
// ---------------------------------------------------------------------------
template<int C>
__global__ __launch_bounds__(256) void gat_agg_kernel(
    const int* __restrict__ rowptr, const int* __restrict__ ssrc,
    const float* __restrict__ as_, const float* __restrict__ ad_,
    const u16* __restrict__ h, float* __restrict__ agg)
{
    const int lane = threadIdx.x & 63;
    const int dst = blockIdx.x * 4 + (threadIdx.x >> 6);
    if (dst >= N_NODES) return;
    const int beg = rowptr[dst], end = rowptr[dst + 1];
    const float add = ad_[dst];
    const int ch = lane & (C - 1);

    float m = -1e30f, l = 0.f, acc = 0.f;
    for (int base = beg; base < end; base += 64) {
        int j = base + lane;
        int sj = 0;
        float sc = -1e30f;
        if (j < end) { sj = ssrc[j]; sc = lrelu(as_[sj] + add); }
        float cm = sc;
        #pragma unroll
        for (int off = 32; off > 0; off >>= 1) cm = fmaxf(cm, __shfl_xor(cm, off));
        float nm = fmaxf(m, cm);
        float scale = __expf(m - nm);
        float ex = (j < end) ? __expf(sc - nm) : 0.f;
        float cs = ex;
        #pragma unroll
        for (int off = 32; off > 0; off >>= 1) cs += __shfl_xor(cs, off);
        l = l * scale + cs;
        acc *= scale;
        m = nm;

        const int cnt = min(64, end - base);
        if (C == 64) {
            for (int jj = 0; jj < cnt; jj += 4) {
                float w0 = __shfl(ex, jj);
                int s0 = __shfl(sj, jj);
                float w1 = (jj + 1 < cnt) ? __shfl(ex, jj + 1) : 0.f;
                int s1 = __shfl(sj, min(jj + 1, cnt - 1));
                float w2 = (jj + 2 < cnt) ? __shfl(ex, jj + 2) : 0.f;
                int s2 = __shfl(sj, min(jj + 2, cnt - 1));
                float w3 = (jj + 3 < cnt) ? __shfl(ex, jj + 3) : 0.f;
                int s3 = __shfl(sj, min(jj + 3, cnt - 1));
                float v0 = bf2f(h[(size_t)s0 * 64 + lane]);
                float v1 = bf2f(h[(size_t)s1 * 64 + lane]);
                float v2 = bf2f(h[(size_t)s2 * 64 + lane]);
                float v3 = bf2f(h[(size_t)s3 * 64 + lane]);
                acc = fmaf(w0, v0, acc);
                acc = fmaf(w1, v1, acc);
                acc = fmaf(w2, v2, acc);
                acc = fmaf(w3, v3, acc);
            }
        } else {
            const int half = lane >> 5;   // two edges per step, 2 steps in flight
            for (int jj = 0; jj < cnt; jj += 4) {
                int j2 = jj + half;
                int j3 = jj + 2 + half;
                float w0 = (j2 < cnt) ? __shfl(ex, j2) : 0.f;
                int s0 = __shfl(sj, min(j2, cnt - 1));
                float w1 = (j3 < cnt) ? __shfl(ex, j3) : 0.f;
                int s1 = __shfl(sj, min(j3, cnt - 1));
                float v0 = bf2f(h[(size_t)s0 * C + ch]);
                float v1 = bf2f(h[(size_t)s1 * C + ch]);
                acc = fmaf(w0, v0, acc);
                acc = fmaf(w1, v1, acc);
            }
        }
    }
    if (C == 32) {
        acc += __shfl_xor(acc, 32);
        if (lane < 32) agg[(size_t)dst * C + ch] = acc / l;
    } else {
        agg[(size_t)dst * C + ch] = acc / l;
    }
}

// ---------------------------------------------------------------------------
// GEMM1: h[N,64](bf16) = x[N,128] @ W[128,64]; as_/ad_ score dots.
// ---------------------------------------------------------------------------
__global__ __launch_bounds__(256) void gemm1_kernel(
    const u32* __restrict__ x32, const u32* __restrict__ W32,
    const void* __restrict__ a_src, const void* __restrict__ a_dst,
    const int* __restrict__ flags,
    u16* __restrict__ h, float* __restrict__ as_, float* __restrict__ ad_)
{
    __shared__ __align__(16) float Wl[128 * 64];
    __shared__ __align__(16) float xs[32 * 132];
    const int tid = threadIdx.x;
    const int node0 = blockIdx.x * 32;
    const int bf = flags[0];

    if (bf) {
        for (int i = tid; i < 4096; i += 256) {
            u32 u = W32[i];
            *(float2*)&Wl[2 * i] = make_float2(__uint_as_float(u << 16),
                                               __uint_as_float(u & 0xFFFF0000u));
        }
        for (int i = tid; i < 2048; i += 256) {
            int nl = i >> 6, kk = i & 63;
            int n = node0 + nl;
            u32 u = (n < N_NODES) ? x32[(size_t)n * 64 + kk] : 0u;
            *(float2*)&xs[nl * 132 + 2 * kk] = make_float2(__uint_as_float(u << 16),
                                                           __uint_as_float(u & 0xFFFF0000u));
        }
    } else {
        for (int i = tid; i < 8192; i += 256) Wl[i] = __uint_as_float(W32[i]);
        for (int i = tid; i < 4096; i += 256) {
            int nl = i >> 7, kk = i & 127;
            int n = node0 + nl;
            xs[nl * 132 + kk] = (n < N_NODES) ? __uint_as_float(x32[(size_t)n * 128 + kk]) : 0.f;
        }
    }
    __syncthreads();

    const int ch0 = (tid & 15) * 4;
    const int n0 = (tid >> 4) * 2;

    float acc0[4] = {0.f, 0.f, 0.f, 0.f}, acc1[4] = {0.f, 0.f, 0.f, 0.f};
    for (int k = 0; k < 128; k += 4) {
        float4 xa = *(const float4*)&xs[n0 * 132 + k];
        float4 xb = *(const float4*)&xs[(n0 + 1) * 132 + k];
        const float* xap = (const float*)&xa;
        const float* xbp = (const float*)&xb;
        #pragma unroll
        for (int kk = 0; kk < 4; ++kk) {
            float4 w = *(const float4*)&Wl[(k + kk) * 64 + ch0];
            float va = xap[kk], vb = xbp[kk];
            acc0[0] += va * w.x; acc0[1] += va * w.y; acc0[2] += va * w.z; acc0[3] += va * w.w;
            acc1[0] += vb * w.x; acc1[1] += vb * w.y; acc1[2] += vb * w.z; acc1[3] += vb * w.w;
        }
    }
    float ps0 = 0.f, ps1 = 0.f, pd0 = 0.f, pd1 = 0.f;
    #pragma unroll
    for (int q = 0; q < 4; ++q) {
        float asv = ldf(a_src, ch0 + q, bf);
        float adv = ldf(a_dst, ch0 + q, bf);
        ps0 += acc0[q] * asv; pd0 += acc0[q] * adv;
        ps1 += acc1[q] * asv; pd1 += acc1[q] * adv;
    }
    #pragma unroll
    for (int off = 1; off < 16; off <<= 1) {
        ps0 += __shfl_xor(ps0, off);
        pd0 += __shfl_xor(pd0, off);
        ps1 += __shfl_xor(ps1, off);
        pd1 += __shfl_xor(pd1, off);
    }
    int na = node0 + n0, nb = na + 1;
    if (na < N_NODES) {
        u32 p0 = (u32)f2bf(acc0[0]) | ((u32)f2bf(acc0[1]) << 16);
        u32 p1 = (u32)f2bf(acc0[2]) | ((u32)f2bf(acc0[3]) << 16);
        *(uint2*)&h[(size_t)na * 64 + ch0] = make_uint2(p0, p1);
        if ((tid & 15) == 0) { as_[na] = ps0; ad_[na] = pd0; }
    }
    if (nb < N_NODES) {
        u32 p0 = (u32)f2bf(acc1[0]) | ((u32)f2bf(acc1[1]) << 16);
        u32 p1 = (u32)f2bf(acc1[2]) | ((u32)f2bf(acc1[3]) << 16);
        *(uint2*)&h[(size_t)nb * 64 + ch0] = make_uint2(p0, p1);
        if ((tid & 15) == 0) { as_[nb] = ps1; ad_[nb] = pd1; }
    }
}

// ---------------------------------------------------------------------------
// GEMM2: hin = relu(agg1 + b1); h2[N,32](bf16) = hin[N,64] @ W[64,32]; alphas.
// ---------------------------------------------------------------------------
__global__ __launch_bounds__(256) void gemm2_kernel(
    const float* __restrict__ agg1, const void* __restrict__ b1,
    const u32* __restrict__ W32, const void* __restrict__ a_src,
    const void* __restrict__ a_dst, const int* __restrict__ flags,
    u16* __restrict__ h, float* __restrict__ as_, float* __restrict__ ad_)
{
    __shared__ __align__(16) float Wl[64 * 32];
    __shared__ __align__(16) float xs[64 * 68];
    const int tid = threadIdx.x;
    const int node0 = blockIdx.x * 64;
    const int bf = flags[0];

    if (bf) {
        for (int i = tid; i < 1024; i += 256) {
            u32 u = W32[i];
            *(float2*)&Wl[2 * i] = make_float2(__uint_as_float(u << 16),
                                               __uint_as_float(u & 0xFFFF0000u));
        }
    } else {
        for (int i = tid; i < 2048; i += 256) Wl[i] = __uint_as_float(W32[i]);
    }
    for (int i = tid; i < 64 * 64; i += 256) {
        int nl = i >> 6, k = i & 63;
        int n = node0 + nl;
        float v = 0.f;
        if (n < N_NODES) v = agg1[(size_t)n * 64 + k] + ldf(b1, k, bf);
        xs[nl * 68 + k] = fmaxf(v, 0.f);
    }
    __syncthreads();

    const int ch0 = (tid & 7) * 4;
    const int n0 = (tid >> 3) * 2;
    float acc0[4] = {0.f, 0.f, 0.f, 0.f}, acc1[4] = {0.f, 0.f, 0.f, 0.f};
    for (int k = 0; k < 64; k += 4) {
        float4 xa = *(const float4*)&xs[n0 * 68 + k];
        float4 xb = *(const float4*)&xs[(n0 + 1) * 68 + k];
        const float* xap = (const float*)&xa;
        const float* xbp = (const float*)&xb;
        #pragma unroll
        for (int kk = 0; kk < 4; ++kk) {
            float4 w = *(const float4*)&Wl[(k + kk) * 32 + ch0];
            float va = xap[kk], vb = xbp[kk];
            acc0[0] += va * w.x; acc0[1] += va * w.y; acc0[2] += va * w.z; acc0[3] += va * w.w;
            acc1[0] += vb * w.x; acc1[1] += vb * w.y; acc1[2] += vb * w.z; acc1[3] += vb * w.w;
        }
    }
    float ps0 = 0.f, ps1 = 0.f, pd0 = 0.f, pd1 = 0.f;
    #pragma unroll
    for (int q = 0; q < 4; ++q) {
        float asv = ldf(a_src, ch0 + q, bf);
        float adv = ldf(a_dst, ch0 + q, bf);
        ps0 += acc0[q] * asv; pd0 += acc0[q] * adv;
        ps1 += acc1[q] * asv; pd1 += acc1[q] * adv;
    }
    #pragma unroll
    for (int off = 1; off < 8; off <<= 1) {
        ps0 += __shfl_xor(ps0, off);
        pd0 += __shfl_xor(pd0, off);
        ps1 += __shfl_xor(ps1, off);
        pd1 += __shfl_xor(pd1, off);
    }
    int na = node0 + n0, nb = na + 1;
    if (na < N_NODES) {
        u32 p0 = (u32)f2bf(acc0[0]) | ((u32)f2bf(acc0[1]) << 16);
        u32 p1 = (u32)f2bf(acc0[2]) | ((u32)f2bf(acc0[3]) << 16);
        *(uint2*)&h[(size_t)na * 32 + ch0] = make_uint2(p0, p1);
        if ((tid & 7) == 0) { as_[na] = ps0; ad_[na] = pd0; }
    }
    if (nb < N_NODES) {
        u32 p0 = (u32)f2bf(acc1[0]) | ((u32)f2bf(acc1[1]) << 16);
        u32 p1 = (u32)f2bf(acc1[2]) | ((u32)f2bf(acc1[3]) << 16);
        *(uint2*)&h[(size_t)nb * 32 + ch0] = make_uint2(p0, p1);
        if ((tid & 7) == 0) { as_[nb] = ps1; ad_[nb] = pd1; }
    }
}

// Final: out = log_softmax(agg2 + b2) per row of 32, float32 store
__global__ __launch_bounds__(256) void lsm_kernel(
    const float* __restrict__ agg2, const void* __restrict__ b2,
    const int* __restrict__ flags, float* __restrict__ out)
{
    int gt = blockIdx.x * 256 + threadIdx.x;
    int n = gt >> 5, c = gt & 31;
    if (n >= N_NODES) return;
    float v = agg2[(size_t)n * 32 + c] + ldf(b2, c, flags[0]);
    float mx = v;
    #pragma unroll
    for (int off = 16; off > 0; off >>= 1) mx = fmaxf(mx, __shfl_xor(mx, off, 32));
    float ex = __expf(v - mx);
    float ss = ex;
    #pragma unroll
    for (int off = 16; off > 0; off >>= 1) ss += __shfl_xor(ss, off, 32);
    out[(size_t)n * 32 + c] = v - mx - __logf(ss);
}

// ---------------------------------------------------------------------------
extern "C" void kernel_launch(void* const* d_in, const int* in_sizes, int n_in,
                              void* d_out, int out_size, void* d_ws, size_t ws_size,
                              hipStream_t stream) {
    const u32* x32  = (const u32*)d_in[0];
    const int* ei   = (const int*)d_in[1];
    const u32* W1   = (const u32*)d_in[2];
    const void* a_s1 = d_in[3];
    const void* a_d1 = d_in[4];
    const void* b1   = d_in[5];
    const u32* W2   = (const u32*)d_in[6];
    const void* a_s2 = d_in[7];
    const void* a_d2 = d_in[8];
    const void* b2   = d_in[9];
    float* out = (float*)d_out;

    // workspace carve-up (~61 MB), all 16B aligned
    char* base = (char*)d_ws;
    int* flags = (int*)base;
    u16* h     = (u16*)(base + 64);                           // N*64 bf16 (reused N*32)
    char* q = base + 64 + (size_t)N_NODES * 64 * 2;
    float* as1 = (float*)q; q += (size_t)N_NODES * 4;
    float* ad1 = (float*)q; q += (size_t)N_NODES * 4;
    float* as2 = (float*)q; q += (size_t)N_NODES * 4;
    float* ad2 = (float*)q; q += (size_t)N_NODES * 4;
    float* agg1 = (float*)q; q += (size_t)N_NODES * 64 * 4;
    float* agg2 = (float*)q; q += (size_t)N_NODES * 32 * 4;
    int* rowptr = (int*)q;  q += (size_t)(N_NODES + 16) * 4;
    int* cursor = (int*)q;  q += (size_t)N_NODES * 4;
    int* bsum   = (int*)q;  q += 2048;
    int* boff   = (int*)q;  q += 2048;
    int* ssrc   = (int*)q;  q += (size_t)ET * 4;
    char* deg0  = q;
    int* deg    = (int*)q;  q += (size_t)N_NODES * 4;
    hipMemsetAsync(deg0, 0, (size_t)N_NODES * 4, stream);

    const int nchunk = (ET + FCHUNK - 1) / FCHUNK;
    const int pgrid = nchunk * NPART;

    detect_kernel<<<1, 64, 0, stream>>>(x32, ei, flags);

    // CSR by dst (shared by both layers), XCD-partitioned scatter
    count_kernel<<<pgrid, 256, 0, stream>>>(ei, flags, deg);
    scan1_kernel<<<SCAN_NB, 256, 0, stream>>>(deg, rowptr, bsum);
    scan2_kernel<<<1, 512, 0, stream>>>(bsum, boff);
    scan3_kernel<<<SCAN_NB, 256, 0, stream>>>(rowptr, boff, cursor);
    fill_kernel<<<pgrid, 256, 0, stream>>>(ei, flags, cursor, ssrc);

    // layer 1
    gemm1_kernel<<<(N_NODES + 31) / 32, 256, 0, stream>>>(x32, W1, a_s1, a_d1, flags, h, as1, ad1);
    gat_agg_kernel<64><<<(N_NODES + 3) / 4, 256, 0, stream>>>(rowptr, ssrc, as1, ad1, h, agg1);

    // layer 2
    gemm2_kernel<<<(N_NODES + 63) / 64, 256, 0, stream>>>(agg1, b1, W2, a_s2, a_d2, flags, h, as2, ad2);
    gat_agg_kernel<32><<<(N_NODES + 3) / 4, 256, 0, stream>>>(rowptr, ssrc, as2, ad2, h, agg2);

    // epilogue
    lsm_kernel<<<(N_NODES * 32 + 255) / 256, 256, 0, stream>>>(agg2, b2, flags, out);
}

// Round 6
// 383.269 us; speedup vs baseline: 2.8792x; 1.3223x over previous
//
#include <hip/hip_runtime.h>

#define N_NODES 100000
#define N_EDGES 1600000
#define ET (N_EDGES + N_NODES)
#define NEG_SLOPE 0.2f

// bucket sort params
#define BSHIFT 9
#define BW 512                                  // nodes per bucket
#define NBUCK ((N_NODES + BW - 1) / BW)         // 196
#define BCAP 10240                              // >25 sigma above mean 8704
#define BINCH 4096                              // edges per bin block

typedef unsigned short u16;
typedef unsigned int u32;

__device__ __forceinline__ float bf2f(u16 v) {
    return __uint_as_float(((u32)v) << 16);
}
__device__ __forceinline__ u16 f2bf(float f) {
    u32 u = __float_as_uint(f);
    u32 r = (u + 0x7FFFu + ((u >> 16) & 1u)) >> 16;  // RNE
    return (u16)r;
}
__device__ __forceinline__ float lrelu(float x) { return x > 0.f ? x : NEG_SLOPE * x; }
__device__ __forceinline__ float ldf(const void* p, int i, int bf) {
    return bf ? bf2f(((const u16*)p)[i]) : ((const float*)p)[i];
}
__device__ __forceinline__ int get_dst(const int* __restrict__ ei, int e, int ei64) {
    if (e < N_EDGES) return ei64 ? ei[2 * (N_EDGES + e)] : ei[N_EDGES + e];
    return e - N_EDGES;
}
__device__ __forceinline__ int get_src(const int* __restrict__ ei, int e, int ei64) {
    if (e < N_EDGES) return ei64 ? ei[2 * e] : ei[e];
    return e - N_EDGES;
}

// ---------------------------------------------------------------------------
// Detect input storage. flags[0]=1 iff floats bf16-stored, flags[1]=1 iff
// edge_index int64-stored. (Measured: both 0 on this dataset.)
// ---------------------------------------------------------------------------
__global__ void detect_kernel(const u32* __restrict__ x32, const int* __restrict__ ei,
                              int* __restrict__ flags) {
    int lane = threadIdx.x;  // 64
    u32 e = (x32[lane] >> 7) & 0xFFu;
    int ok = (e >= 96u && e <= 143u) ? 1 : 0;
    int cnt = (int)__popcll(__ballot(ok));
    int nz = (ei[2 * lane + 1] != 0) + (ei[2 * (lane + 64) + 1] != 0);
    #pragma unroll
    for (int off = 32; off > 0; off >>= 1) nz += __shfl_xor(nz, off);
    if (lane == 0) { flags[0] = (cnt >= 48) ? 1 : 0; flags[1] = (nz == 0) ? 1 : 0; }
}

// ---------------------------------------------------------------------------
// Pass 1: bin edges into NBUCK buckets by dst>>9. Per-block LDS histogram,
// one global atomic per touched bucket, packed code = (dst&511)<<17 | src.
// ---------------------------------------------------------------------------
__global__ __launch_bounds__(256) void bin_kernel(
    const int* __restrict__ ei, const int* __restrict__ flags,
    int* __restrict__ bcnt, u32* __restrict__ bbuf)
{
    __shared__ int hist[NBUCK];
    const int t = threadIdx.x;
    const int base = blockIdx.x * BINCH;
    const int ei64 = flags[1];
    for (int i = t; i < NBUCK; i += 256) hist[i] = 0;
    __syncthreads();
    for (int i = t; i < BINCH; i += 256) {
        int e = base + i;
        if (e >= ET) break;
        int d = get_dst(ei, e, ei64);
        atomicAdd(&hist[d >> BSHIFT], 1);
    }
    __syncthreads();
    // reserve global ranges; reuse hist as running cursor
    for (int i = t; i < NBUCK; i += 256) {
        int c = hist[i];
        hist[i] = (c > 0) ? atomicAdd(&bcnt[i], c) : 0;
    }
    __syncthreads();
    for (int i = t; i < BINCH; i += 256) {
        int e = base + i;
        if (e >= ET) break;
        int d = get_dst(ei, e, ei64);
        int s = get_src(ei, e, ei64);
        int b = d >> BSHIFT;
        int pos = atomicAdd(&hist[b], 1);
        if (pos < BCAP)
            bbuf[(size_t)b * BCAP + pos] = ((u32)(d & (BW - 1)) << 17) | (u32)s;
    }
}

// exclusive scan of clamped bucket counts -> bbase[NBUCK+1]
__global__ __launch_bounds__(256) void bscan_kernel(
    const int* __restrict__ bcnt, int* __restrict__ bbase)
{
    __shared__ int sd[256];
    int t = threadIdx.x;
    int v = (t < NBUCK) ? min(bcnt[t], BCAP) : 0;
    sd[t] = v;
    __syncthreads();
    for (int off = 1; off < 256; off <<= 1) {
        int x = (t >= off) ? sd[t - off] : 0;
        __syncthreads();
        sd[t] += x;
        __syncthreads();
    }
    if (t < NBUCK) bbase[t] = sd[t] - v;
    if (t == NBUCK - 1) bbase[NBUCK] = sd[t];
}

// ---------------------------------------------------------------------------
// Pass 2: one block per bucket. Histogram codes -> local scan -> write rowptr,
// scatter src into LDS window, coalesced copy-out to ssrc.
// ---------------------------------------------------------------------------
__global__ __launch_bounds__(256) void scatter_kernel(
    const int* __restrict__ bcnt, const int* __restrict__ bbase,
    const u32* __restrict__ bbuf, int* __restrict__ rowptr, int* __restrict__ ssrc)
{
    __shared__ int hist[BW];
    __shared__ int cur[BW];
    __shared__ int wtot[4];
    __shared__ int lds_s[BCAP];
    const int t = threadIdx.x;
    const int b = blockIdx.x;
    const int cnt = min(bcnt[b], BCAP);
    const int base = bbase[b];
    const u32* mybuf = bbuf + (size_t)b * BCAP;

    hist[t] = 0; hist[t + 256] = 0;
    __syncthreads();
    for (int i = t; i < cnt; i += 256) {
        int ld = (int)(mybuf[i] >> 17);
        atomicAdd(&hist[ld], 1);
    }
    __syncthreads();
    // scan 512 entries: pair-sum + wave scan + wave-total fixup
    int a0 = hist[2 * t], a1 = hist[2 * t + 1];
    int s = a0 + a1;
    int lane = t & 63, wid = t >> 6;
    int v = s;
    #pragma unroll
    for (int off = 1; off < 64; off <<= 1) {
        int n = __shfl_up(v, off);
        if (lane >= off) v += n;
    }
    if (lane == 63) wtot[wid] = v;
    __syncthreads();
    if (t == 0) {
        int acc = 0;
        #pragma unroll
        for (int w = 0; w < 4; ++w) { int tmp = wtot[w]; wtot[w] = acc; acc += tmp; }
    }
    __syncthreads();
    int excl_pair = v + wtot[wid] - s;   // exclusive prefix of pair 2t
    cur[2 * t] = excl_pair;
    cur[2 * t + 1] = excl_pair + a0;
    __syncthreads();
    // write rowptr before cur is mutated
    for (int li = t; li < BW; li += 256) {
        int g = b * BW + li;
        if (g < N_NODES) rowptr[g] = base + cur[li];
    }
    if (b == NBUCK - 1 && t == 0) rowptr[N_NODES] = bbase[NBUCK];
    __syncthreads();
    // scatter into LDS window
    for (int i = t; i < cnt; i += 256) {
        u32 code = mybuf[i];
        int ld = (int)(code >> 17);
        int pos = atomicAdd(&cur[ld], 1);
        lds_s[pos] = (int)(code & 0x1FFFFu);
    }
    __syncthreads();
    // coalesced copy-out
    for (int i = t; i < cnt; i += 256) ssrc[base + i] = lds_s[i];
}

// ---------------------------------------------------------------------------
// GEMM1: h[N,64](bf16) = x[N,128] @ W[128,64]; as_/ad_ score dots.
// 256 nodes/block, 256 threads, thread = 8 nodes x 8 ch, k-chunks of 32.
// ---------------------------------------------------------------------------
__global__ __launch_bounds__(256) void gemm1_kernel(
    const float* __restrict__ x, const float* __restrict__ W,
    const void* __restrict__ a_src, const void* __restrict__ a_dst,
    const int* __restrict__ flags,
    u16* __restrict__ h, float* __restrict__ as_, float* __restrict__ ad_)
{
    __shared__ float xs[256 * 33];   // 33.8 KB, stride 33: conflict-free
    __shared__ float Wl[32 * 64];    // 8 KB
    const int t = threadIdx.x;
    const int node0 = blockIdx.x * 256;
    const int bf = flags[0];
    const int ng = t >> 3;           // 0..31 -> nodes ng*8..+7
    const int cg = t & 7;            // 0..7  -> ch cg*8..+7

    float acc[8][8];
    #pragma unroll
    for (int i = 0; i < 8; ++i)
        #pragma unroll
        for (int j = 0; j < 8; ++j) acc[i][j] = 0.f;

    for (int kc = 0; kc < 4; ++kc) {
        const int kb = kc * 32;
        // stage x chunk: 256 nodes x 32 k
        const int c4 = t & 7;        // float4 col within 128B row-chunk
        #pragma unroll
        for (int p = 0; p < 8; ++p) {
            int row = (t >> 3) + p * 32;
            int n = node0 + row;
            float4 vv = make_float4(0.f, 0.f, 0.f, 0.f);
            if (n < N_NODES) {
                if (!bf) {
                    vv = *(const float4*)(x + (size_t)n * 128 + kb + c4 * 4);
                } else {
                    const u16* xh = (const u16*)x;
                    vv.x = bf2f(xh[(size_t)n * 128 + kb + c4 * 4 + 0]);
                    vv.y = bf2f(xh[(size_t)n * 128 + kb + c4 * 4 + 1]);
                    vv.z = bf2f(xh[(size_t)n * 128 + kb + c4 * 4 + 2]);
                    vv.w = bf2f(xh[(size_t)n * 128 + kb + c4 * 4 + 3]);
                }
            }
            float* dstp = &xs[row * 33 + c4 * 4];
            dstp[0] = vv.x; dstp[1] = vv.y; dstp[2] = vv.z; dstp[3] = vv.w;
        }
        // stage W chunk: 32 k x 64 ch
        if (!bf) {
            #pragma unroll
            for (int qq = 0; qq < 2; ++qq) {
                int f4 = t * 2 + qq;
                ((float4*)Wl)[f4] = ((const float4*)(W + (size_t)kb * 64))[f4];
            }
        } else {
            const u16* Wh = (const u16*)W;
            for (int i = t; i < 2048; i += 256) Wl[i] = bf2f(Wh[(size_t)kb * 64 + i]);
        }
        __syncthreads();

        for (int kk = 0; kk < 32; ++kk) {
            float xr[8];
            #pragma unroll
            for (int i = 0; i < 8; ++i) xr[i] = xs[(ng * 8 + i) * 33 + kk];
            float4 w0 = *(const float4*)&Wl[kk * 64 + cg * 8];
            float4 w1 = *(const float4*)&Wl[kk * 64 + cg * 8 + 4];
            const float wr[8] = {w0.x, w0.y, w0.z, w0.w, w1.x, w1.y, w1.z, w1.w};
            #pragma unroll
            for (int i = 0; i < 8; ++i)
                #pragma unroll
                for (int j = 0; j < 8; ++j)
                    acc[i][j] = fmaf(xr[i], wr[j], acc[i][j]);
        }
        __syncthreads();
    }

    float av[8], dv[8];
    #pragma unroll
    for (int j = 0; j < 8; ++j) {
        av[j] = ldf(a_src, cg * 8 + j, bf);
        dv[j] = ldf(a_dst, cg * 8 + j, bf);
    }
    #pragma unroll
    for (int i = 0; i < 8; ++i) {
        int n = node0 + ng * 8 + i;
        float ps = 0.f, pd = 0.f;
        #pragma unroll
        for (int j = 0; j < 8; ++j) { ps += acc[i][j] * av[j]; pd += acc[i][j] * dv[j]; }
        #pragma unroll
        for (int off = 1; off < 8; off <<= 1) {
            ps += __shfl_xor(ps, off);
            pd += __shfl_xor(pd, off);
        }
        if (n < N_NODES) {
            uint4 hv;
            hv.x = (u32)f2bf(acc[i][0]) | ((u32)f2bf(acc[i][1]) << 16);
            hv.y = (u32)f2bf(acc[i][2]) | ((u32)f2bf(acc[i][3]) << 16);
            hv.z = (u32)f2bf(acc[i][4]) | ((u32)f2bf(acc[i][5]) << 16);
            hv.w = (u32)f2bf(acc[i][6]) | ((u32)f2bf(acc[i][7]) << 16);
            *(uint4*)&h[(size_t)n * 64 + cg * 8] = hv;
            if (cg == 0) { as_[n] = ps; ad_[n] = pd; }
        }
    }
}

// ---------------------------------------------------------------------------
// Fused per-dst GAT aggregation (online softmax, no atomics).
// ---------------------------------------------------------------------------
template<int C>
__global__ __launch_bounds__(256) void gat_agg_kernel(
    const int* __restrict__ rowptr, const int* __restrict__ ssrc,
    const float* __restrict__ as_, const float* __restrict__ ad_,
    const u16* __restrict__ h, float* __restrict__ agg)
{
    const int lane = threadIdx.x & 63;
    const int dst = blockIdx.x * 4 + (threadIdx.x >> 6);
    if (dst >= N_NODES) return;
    const int beg = rowptr[dst], end = rowptr[dst + 1];
    const float add = ad_[dst];
    const int ch = lane & (C - 1);

    float m = -1e30f, l = 0.f, acc = 0.f;
    for (int base = beg; base < end; base += 64) {
        int j = base + lane;
        int sj = 0;
        float sc = -1e30f;
        if (j < end) { sj = ssrc[j]; sc = lrelu(as_[sj] + add); }
        float cm = sc;
        #pragma unroll
        for (int off = 32; off > 0; off >>= 1) cm = fmaxf(cm, __shfl_xor(cm, off));
        float nm = fmaxf(m, cm);
        float scale = __expf(m - nm);
        float ex = (j < end) ? __expf(sc - nm) : 0.f;
        float cs = ex;
        #pragma unroll
        for (int off = 32; off > 0; off >>= 1) cs += __shfl_xor(cs, off);
        l = l * scale + cs;
        acc *= scale;
        m = nm;

        const int cnt = min(64, end - base);
        if (C == 64) {
            for (int jj = 0; jj < cnt; jj += 4) {
                float w0 = __shfl(ex, jj);
                int s0 = __shfl(sj, jj);
                float w1 = (jj + 1 < cnt) ? __shfl(ex, jj + 1) : 0.f;
                int s1 = __shfl(sj, min(jj + 1, cnt - 1));
                float w2 = (jj + 2 < cnt) ? __shfl(ex, jj + 2) : 0.f;
                int s2 = __shfl(sj, min(jj + 2, cnt - 1));
                float w3 = (jj + 3 < cnt) ? __shfl(ex, jj + 3) : 0.f;
                int s3 = __shfl(sj, min(jj + 3, cnt - 1));
                float v0 = bf2f(h[(size_t)s0 * 64 + lane]);
                float v1 = bf2f(h[(size_t)s1 * 64 + lane]);
                float v2 = bf2f(h[(size_t)s2 * 64 + lane]);
                float v3 = bf2f(h[(size_t)s3 * 64 + lane]);
                acc = fmaf(w0, v0, acc);
                acc = fmaf(w1, v1, acc);
                acc = fmaf(w2, v2, acc);
                acc = fmaf(w3, v3, acc);
            }
        } else {
            const int half = lane >> 5;
            for (int jj = 0; jj < cnt; jj += 4) {
                int j2 = jj + half;
                int j3 = jj + 2 + half;
                float w0 = (j2 < cnt) ? __shfl(ex, j2) : 0.f;
                int s0 = __shfl(sj, min(j2, cnt - 1));
                float w1 = (j3 < cnt) ? __shfl(ex, j3) : 0.f;
                int s1 = __shfl(sj, min(j3, cnt - 1));
                float v0 = bf2f(h[(size_t)s0 * C + ch]);
                float v1 = bf2f(h[(size_t)s1 * C + ch]);
                acc = fmaf(w0, v0, acc);
                acc = fmaf(w1, v1, acc);
            }
        }
    }
    if (C == 32) {
        acc += __shfl_xor(acc, 32);
        if (lane < 32) agg[(size_t)dst * C + ch] = acc / l;
    } else {
        agg[(size_t)dst * C + ch] = acc / l;
    }
}

// ---------------------------------------------------------------------------
// GEMM2: hin = relu(agg1 + b1); h2[N,32](bf16) = hin[N,64] @ W[64,32]; alphas.
// ---------------------------------------------------------------------------
__global__ __launch_bounds__(256) void gemm2_kernel(
    const float* __restrict__ agg1, const void* __restrict__ b1,
    const u32* __restrict__ W32, const void* __restrict__ a_src,
    const void* __restrict__ a_dst, const int* __restrict__ flags,
    u16* __restrict__ h, float* __restrict__ as_, float* __restrict__ ad_)
{
    __shared__ __align__(16) float Wl[64 * 32];
    __shared__ __align__(16) float xs[64 * 68];
    const int tid = threadIdx.x;
    const int node0 = blockIdx.x * 64;
    const int bf = flags[0];

    if (bf) {
        for (int i = tid; i < 1024; i += 256) {
            u32 u = W32[i];
            *(float2*)&Wl[2 * i] = make_float2(__uint_as_float(u << 16),
                                               __uint_as_float(u & 0xFFFF0000u));
        }
    } else {
        for (int i = tid; i < 2048; i += 256) Wl[i] = __uint_as_float(W32[i]);
    }
    for (int i = tid; i < 64 * 64; i += 256) {
        int nl = i >> 6, k = i & 63;
        int n = node0 + nl;
        float v = 0.f;
        if (n < N_NODES) v = agg1[(size_t)n * 64 + k] + ldf(b1, k, bf);
        xs[nl * 68 + k] = fmaxf(v, 0.f);
    }
    __syncthreads();

    const int ch0 = (tid & 7) * 4;
    const int n0 = (tid >> 3) * 2;
    float acc0[4] = {0.f, 0.f, 0.f, 0.f}, acc1[4] = {0.f, 0.f, 0.f, 0.f};
    for (int k = 0; k < 64; k += 4) {
        float4 xa = *(const float4*)&xs[n0 * 68 + k];
        float4 xb = *(const float4*)&xs[(n0 + 1) * 68 + k];
        const float* xap = (const float*)&xa;
        const float* xbp = (const float*)&xb;
        #pragma unroll
        for (int kk = 0; kk < 4; ++kk) {
            float4 w = *(const float4*)&Wl[(k + kk) * 32 + ch0];
            float va = xap[kk], vb = xbp[kk];
            acc0[0] += va * w.x; acc0[1] += va * w.y; acc0[2] += va * w.z; acc0[3] += va * w.w;
            acc1[0] += vb * w.x; acc1[1] += vb * w.y; acc1[2] += vb * w.z; acc1[3] += vb * w.w;
        }
    }
    float ps0 = 0.f, ps1 = 0.f, pd0 = 0.f, pd1 = 0.f;
    #pragma unroll
    for (int q = 0; q < 4; ++q) {
        float asv = ldf(a_src, ch0 + q, bf);
        float adv = ldf(a_dst, ch0 + q, bf);
        ps0 += acc0[q] * asv; pd0 += acc0[q] * adv;
        ps1 += acc1[q] * asv; pd1 += acc1[q] * adv;
    }
    #pragma unroll
    for (int off = 1; off < 8; off <<= 1) {
        ps0 += __shfl_xor(ps0, off);
        pd0 += __shfl_xor(pd0, off);
        ps1 += __shfl_xor(ps1, off);
        pd1 += __shfl_xor(pd1, off);
    }
    int na = node0 + n0, nb = na + 1;
    if (na < N_NODES) {
        u32 p0 = (u32)f2bf(acc0[0]) | ((u32)f2bf(acc0[1]) << 16);
        u32 p1 = (u32)f2bf(acc0[2]) | ((u32)f2bf(acc0[3]) << 16);
        *(uint2*)&h[(size_t)na * 32 + ch0] = make_uint2(p0, p1);
        if ((tid & 7) == 0) { as_[na] = ps0; ad_[na] = pd0; }
    }
    if (nb < N_NODES) {
        u32 p0 = (u32)f2bf(acc1[0]) | ((u32)f2bf(acc1[1]) << 16);
        u32 p1 = (u32)f2bf(acc1[2]) | ((u32)f2bf(acc1[3]) << 16);
        *(uint2*)&h[(size_t)nb * 32 + ch0] = make_uint2(p0, p1);
        if ((tid & 7) == 0) { as_[nb] = ps1; ad_[nb] = pd1; }
    }
}

// Final: out = log_softmax(agg2 + b2) per row of 32, float32 store
__global__ __launch_bounds__(256) void lsm_kernel(
    const float* __restrict__ agg2, const void* __restrict__ b2,
    const int* __restrict__ flags, float* __restrict__ out)
{
    int gt = blockIdx.x * 256 + threadIdx.x;
    int n = gt >> 5, c = gt & 31;
    if (n >= N_NODES) return;
    float v = agg2[(size_t)n * 32 + c] + ldf(b2, c, flags[0]);
    float mx = v;
    #pragma unroll
    for (int off = 16; off > 0; off >>= 1) mx = fmaxf(mx, __shfl_xor(mx, off, 32));
    float ex = __expf(v - mx);
    float ss = ex;
    #pragma unroll
    for (int off = 16; off > 0; off >>= 1) ss += __shfl_xor(ss, off, 32);
    out[(size_t)n * 32 + c] = v - mx - __logf(ss);
}

// ---------------------------------------------------------------------------
extern "C" void kernel_launch(void* const* d_in, const int* in_sizes, int n_in,
                              void* d_out, int out_size, void* d_ws, size_t ws_size,
                              hipStream_t stream) {
    const float* x   = (const float*)d_in[0];
    const int* ei    = (const int*)d_in[1];
    const float* W1  = (const float*)d_in[2];
    const void* a_s1 = d_in[3];
    const void* a_d1 = d_in[4];
    const void* b1   = d_in[5];
    const u32* W2    = (const u32*)d_in[6];
    const void* a_s2 = d_in[7];
    const void* a_d2 = d_in[8];
    const void* b2   = d_in[9];
    float* out = (float*)d_out;

    // workspace carve-up (~60 MB); bbuf aliases agg2 (disjoint lifetimes)
    char* base = (char*)d_ws;
    int* flags = (int*)base;
    u16* h     = (u16*)(base + 64);                           // N*64 bf16 (reused N*32)
    char* q = base + 64 + (size_t)N_NODES * 64 * 2;
    float* as1 = (float*)q; q += (size_t)N_NODES * 4;
    float* ad1 = (float*)q; q += (size_t)N_NODES * 4;
    float* as2 = (float*)q; q += (size_t)N_NODES * 4;
    float* ad2 = (float*)q; q += (size_t)N_NODES * 4;
    float* agg1 = (float*)q; q += (size_t)N_NODES * 64 * 4;
    float* agg2 = (float*)q; q += (size_t)N_NODES * 32 * 4;   // 12.8 MB
    u32*  bbuf  = (u32*)agg2;                                 // 8.03 MB alias
    int* rowptr = (int*)q;  q += (size_t)(N_NODES + 16) * 4;
    int* ssrc   = (int*)q;  q += (size_t)ET * 4;
    int* bcnt   = (int*)q;  q += 256 * 4;
    int* bbase  = (int*)q;  q += 256 * 4;
    hipMemsetAsync(bcnt, 0, 256 * 4, stream);

    detect_kernel<<<1, 64, 0, stream>>>((const u32*)x, ei, flags);

    // CSR by dst via 2-pass bucket sort (rowptr built in scatter)
    bin_kernel<<<(ET + BINCH - 1) / BINCH, 256, 0, stream>>>(ei, flags, bcnt, bbuf);
    bscan_kernel<<<1, 256, 0, stream>>>(bcnt, bbase);
    scatter_kernel<<<NBUCK, 256, 0, stream>>>(bcnt, bbase, bbuf, rowptr, ssrc);

    // layer 1
    gemm1_kernel<<<(N_NODES + 255) / 256, 256, 0, stream>>>(x, W1, a_s1, a_d1, flags, h, as1, ad1);
    gat_agg_kernel<64><<<(N_NODES + 3) / 4, 256, 0, stream>>>(rowptr, ssrc, as1, ad1, h, agg1);

    // layer 2
    gemm2_kernel<<<(N_NODES + 63) / 64, 256, 0, stream>>>(agg1, b1, W2, a_s2, a_d2, flags, h, as2, ad2);
    gat_agg_kernel<32><<<(N_NODES + 3) / 4, 256, 0, stream>>>(rowptr, ssrc, as2, ad2, h, agg2);

    // epilogue
    lsm_kernel<<<(N_NODES * 32 + 255) / 256, 256, 0, stream>>>(agg2, b2, flags, out);
}

// Round 9
// 377.170 us; speedup vs baseline: 2.9258x; 1.0162x over previous
//
#include <hip/hip_runtime.h>

#define N_NODES 100000
#define N_EDGES 1600000
#define ET (N_EDGES + N_NODES)
#define NEG_SLOPE 0.2f

// bucket sort params (round-6 verified)
#define BSHIFT 9
#define BW 512                                  // nodes per bucket
#define NBUCK ((N_NODES + BW - 1) / BW)         // 196
#define BCAP 10240
#define BINCH 4096                              // edges per bin block

typedef unsigned short u16;
typedef unsigned int u32;

__device__ __forceinline__ float bf2f(u16 v) {
    return __uint_as_float(((u32)v) << 16);
}
__device__ __forceinline__ u16 f2bf(float f) {
    u32 u = __float_as_uint(f);
    u32 r = (u + 0x7FFFu + ((u >> 16) & 1u)) >> 16;  // RNE
    return (u16)r;
}
__device__ __forceinline__ float lrelu(float x) { return x > 0.f ? x : NEG_SLOPE * x; }
__device__ __forceinline__ float ldf(const void* p, int i, int bf) {
    return bf ? bf2f(((const u16*)p)[i]) : ((const float*)p)[i];
}
__device__ __forceinline__ int get_dst(const int* __restrict__ ei, int e, int ei64) {
    if (e < N_EDGES) return ei64 ? ei[2 * (N_EDGES + e)] : ei[N_EDGES + e];
    return e - N_EDGES;
}
__device__ __forceinline__ int get_src(const int* __restrict__ ei, int e, int ei64) {
    if (e < N_EDGES) return ei64 ? ei[2 * e] : ei[e];
    return e - N_EDGES;
}

// ---------------------------------------------------------------------------
__global__ void detect_kernel(const u32* __restrict__ x32, const int* __restrict__ ei,
                              int* __restrict__ flags) {
    int lane = threadIdx.x;  // 64
    u32 e = (x32[lane] >> 7) & 0xFFu;
    int ok = (e >= 96u && e <= 143u) ? 1 : 0;
    int cnt = (int)__popcll(__ballot(ok));
    int nz = (ei[2 * lane + 1] != 0) + (ei[2 * (lane + 64) + 1] != 0);
    #pragma unroll
    for (int off = 32; off > 0; off >>= 1) nz += __shfl_xor(nz, off);
    if (lane == 0) { flags[0] = (cnt >= 48) ? 1 : 0; flags[1] = (nz == 0) ? 1 : 0; }
}

// ---------------------------------------------------------------------------
// Pass 1: bin edges by dst>>9 into 196 buckets; code = (dst&511)<<17 | src.
// ---------------------------------------------------------------------------
__global__ __launch_bounds__(256) void bin_kernel(
    const int* __restrict__ ei, const int* __restrict__ flags,
    int* __restrict__ bcnt, u32* __restrict__ bbuf)
{
    __shared__ int hist[NBUCK];
    const int t = threadIdx.x;
    const int base = blockIdx.x * BINCH;
    const int ei64 = flags[1];
    for (int i = t; i < NBUCK; i += 256) hist[i] = 0;
    __syncthreads();
    for (int i = t; i < BINCH; i += 256) {
        int e = base + i;
        if (e >= ET) break;
        int d = get_dst(ei, e, ei64);
        atomicAdd(&hist[d >> BSHIFT], 1);
    }
    __syncthreads();
    for (int i = t; i < NBUCK; i += 256) {
        int c = hist[i];
        hist[i] = (c > 0) ? atomicAdd(&bcnt[i], c) : 0;
    }
    __syncthreads();
    for (int i = t; i < BINCH; i += 256) {
        int e = base + i;
        if (e >= ET) break;
        int d = get_dst(ei, e, ei64);
        int s = get_src(ei, e, ei64);
        int b = d >> BSHIFT;
        int pos = atomicAdd(&hist[b], 1);
        if (pos < BCAP)
            bbuf[(size_t)b * BCAP + pos] = ((u32)(d & (BW - 1)) << 17) | (u32)s;
    }
}

// exclusive scan of clamped bucket counts -> bbase[NBUCK+1]
__global__ __launch_bounds__(256) void bscan_kernel(
    const int* __restrict__ bcnt, int* __restrict__ bbase)
{
    __shared__ int sd[256];
    int t = threadIdx.x;
    int v = (t < NBUCK) ? min(bcnt[t], BCAP) : 0;
    sd[t] = v;
    __syncthreads();
    for (int off = 1; off < 256; off <<= 1) {
        int x = (t >= off) ? sd[t - off] : 0;
        __syncthreads();
        sd[t] += x;
        __syncthreads();
    }
    if (t < NBUCK) bbase[t] = sd[t] - v;
    if (t == NBUCK - 1) bbase[NBUCK] = sd[t];
}

// ---------------------------------------------------------------------------
// Pass 2: one block per bucket -> rowptr + dst-sorted ssrc.
// ---------------------------------------------------------------------------
__global__ __launch_bounds__(256) void scatter_kernel(
    const int* __restrict__ bcnt, const int* __restrict__ bbase,
    const u32* __restrict__ bbuf, int* __restrict__ rowptr, int* __restrict__ ssrc)
{
    __shared__ int hist[BW];
    __shared__ int cur[BW];
    __shared__ int wtot[4];
    __shared__ int lds_s[BCAP];
    const int t = threadIdx.x;
    const int b = blockIdx.x;
    const int cnt = min(bcnt[b], BCAP);
    const int base = bbase[b];
    const u32* mybuf = bbuf + (size_t)b * BCAP;

    hist[t] = 0; hist[t + 256] = 0;
    __syncthreads();
    for (int i = t; i < cnt; i += 256) {
        int ld = (int)(mybuf[i] >> 17);
        atomicAdd(&hist[ld], 1);
    }
    __syncthreads();
    int a0 = hist[2 * t], a1 = hist[2 * t + 1];
    int s = a0 + a1;
    int lane = t & 63, wid = t >> 6;
    int v = s;
    #pragma unroll
    for (int off = 1; off < 64; off <<= 1) {
        int n = __shfl_up(v, off);
        if (lane >= off) v += n;
    }
    if (lane == 63) wtot[wid] = v;
    __syncthreads();
    if (t == 0) {
        int acc = 0;
        #pragma unroll
        for (int w = 0; w < 4; ++w) { int tmp = wtot[w]; wtot[w] = acc; acc += tmp; }
    }
    __syncthreads();
    int excl_pair = v + wtot[wid] - s;
    cur[2 * t] = excl_pair;
    cur[2 * t + 1] = excl_pair + a0;
    __syncthreads();
    for (int li = t; li < BW; li += 256) {
        int g = b * BW + li;
        if (g < N_NODES) rowptr[g] = base + cur[li];
    }
    if (b == NBUCK - 1 && t == 0) rowptr[N_NODES] = bbase[NBUCK];
    __syncthreads();
    for (int i = t; i < cnt; i += 256) {
        u32 code = mybuf[i];
        int ld = (int)(code >> 17);
        int pos = atomicAdd(&cur[ld], 1);
        lds_s[pos] = (int)(code & 0x1FFFFu);
    }
    __syncthreads();
    for (int i = t; i < cnt; i += 256) ssrc[base + i] = lds_s[i];
}

// ---------------------------------------------------------------------------
// GEMM1: h[N,64](bf16) = x[N,128] @ W[128,64]; as_/ad_ score dots.
// ---------------------------------------------------------------------------
__global__ __launch_bounds__(256) void gemm1_kernel(
    const float* __restrict__ x, const float* __restrict__ W,
    const void* __restrict__ a_src, const void* __restrict__ a_dst,
    const int* __restrict__ flags,
    u16* __restrict__ h, float* __restrict__ as_, float* __restrict__ ad_)
{
    __shared__ float xs[256 * 33];   // 33.8 KB
    __shared__ float Wl[32 * 64];    // 8 KB
    const int t = threadIdx.x;
    const int node0 = blockIdx.x * 256;
    const int bf = flags[0];
    const int ng = t >> 3;
    const int cg = t & 7;

    float acc[8][8];
    #pragma unroll
    for (int i = 0; i < 8; ++i)
        #pragma unroll
        for (int j = 0; j < 8; ++j) acc[i][j] = 0.f;

    for (int kc = 0; kc < 4; ++kc) {
        const int kb = kc * 32;
        const int c4 = t & 7;
        #pragma unroll
        for (int p = 0; p < 8; ++p) {
            int row = (t >> 3) + p * 32;
            int n = node0 + row;
            float4 vv = make_float4(0.f, 0.f, 0.f, 0.f);
            if (n < N_NODES) {
                if (!bf) {
                    vv = *(const float4*)(x + (size_t)n * 128 + kb + c4 * 4);
                } else {
                    const u16* xh = (const u16*)x;
                    vv.x = bf2f(xh[(size_t)n * 128 + kb + c4 * 4 + 0]);
                    vv.y = bf2f(xh[(size_t)n * 128 + kb + c4 * 4 + 1]);
                    vv.z = bf2f(xh[(size_t)n * 128 + kb + c4 * 4 + 2]);
                    vv.w = bf2f(xh[(size_t)n * 128 + kb + c4 * 4 + 3]);
                }
            }
            float* dstp = &xs[row * 33 + c4 * 4];
            dstp[0] = vv.x; dstp[1] = vv.y; dstp[2] = vv.z; dstp[3] = vv.w;
        }
        if (!bf) {
            #pragma unroll
            for (int qq = 0; qq < 2; ++qq) {
                int f4 = t * 2 + qq;
                ((float4*)Wl)[f4] = ((const float4*)(W + (size_t)kb * 64))[f4];
            }
        } else {
            const u16* Wh = (const u16*)W;
            for (int i = t; i < 2048; i += 256) Wl[i] = bf2f(Wh[(size_t)kb * 64 + i]);
        }
        __syncthreads();

        for (int kk = 0; kk < 32; ++kk) {
            float xr[8];
            #pragma unroll
            for (int i = 0; i < 8; ++i) xr[i] = xs[(ng * 8 + i) * 33 + kk];
            float4 w0 = *(const float4*)&Wl[kk * 64 + cg * 8];
            float4 w1 = *(const float4*)&Wl[kk * 64 + cg * 8 + 4];
            const float wr[8] = {w0.x, w0.y, w0.z, w0.w, w1.x, w1.y, w1.z, w1.w};
            #pragma unroll
            for (int i = 0; i < 8; ++i)
                #pragma unroll
                for (int j = 0; j < 8; ++j)
                    acc[i][j] = fmaf(xr[i], wr[j], acc[i][j]);
        }
        __syncthreads();
    }

    float av[8], dv[8];
    #pragma unroll
    for (int j = 0; j < 8; ++j) {
        av[j] = ldf(a_src, cg * 8 + j, bf);
        dv[j] = ldf(a_dst, cg * 8 + j, bf);
    }
    #pragma unroll
    for (int i = 0; i < 8; ++i) {
        int n = node0 + ng * 8 + i;
        float ps = 0.f, pd = 0.f;
        #pragma unroll
        for (int j = 0; j < 8; ++j) { ps += acc[i][j] * av[j]; pd += acc[i][j] * dv[j]; }
        #pragma unroll
        for (int off = 1; off < 8; off <<= 1) {
            ps += __shfl_xor(ps, off);
            pd += __shfl_xor(pd, off);
        }
        if (n < N_NODES) {
            uint4 hv;
            hv.x = (u32)f2bf(acc[i][0]) | ((u32)f2bf(acc[i][1]) << 16);
            hv.y = (u32)f2bf(acc[i][2]) | ((u32)f2bf(acc[i][3]) << 16);
            hv.z = (u32)f2bf(acc[i][4]) | ((u32)f2bf(acc[i][5]) << 16);
            hv.w = (u32)f2bf(acc[i][6]) | ((u32)f2bf(acc[i][7]) << 16);
            *(uint4*)&h[(size_t)n * 64 + cg * 8] = hv;
            if (cg == 0) { as_[n] = ps; ad_[n] = pd; }
        }
    }
}

// ---------------------------------------------------------------------------
// Fused per-dst GAT aggregation (r6-verified template; unroll widened only).
// One wave per dst. C=64: lane=channel, all lanes process all edges with
// wave-uniform broadcast index. C=32: validated 2-group half-split.
// ---------------------------------------------------------------------------
template<int C>
__global__ __launch_bounds__(256) void gat_agg_kernel(
    const int* __restrict__ rowptr, const int* __restrict__ ssrc,
    const float* __restrict__ as_, const float* __restrict__ ad_,
    const u16* __restrict__ h, float* __restrict__ agg)
{
    const int lane = threadIdx.x & 63;
    const int dst = blockIdx.x * 4 + (threadIdx.x >> 6);
    if (dst >= N_NODES) return;
    const int beg = rowptr[dst], end = rowptr[dst + 1];
    const float add = ad_[dst];
    const int ch = lane & (C - 1);

    float m = -1e30f, l = 0.f, acc = 0.f;
    for (int base = beg; base < end; base += 64) {
        int j = base + lane;
        int sj = 0;
        float sc = -1e30f;
        if (j < end) { sj = ssrc[j]; sc = lrelu(as_[sj] + add); }
        float cm = sc;
        #pragma unroll
        for (int off = 32; off > 0; off >>= 1) cm = fmaxf(cm, __shfl_xor(cm, off));
        float nm = fmaxf(m, cm);
        float scale = __expf(m - nm);
        float ex = (j < end) ? __expf(sc - nm) : 0.f;
        float cs = ex;
        #pragma unroll
        for (int off = 32; off > 0; off >>= 1) cs += __shfl_xor(cs, off);
        l = l * scale + cs;
        acc *= scale;
        m = nm;

        const int cnt = min(64, end - base);
        if (C == 64) {
            // 8 independent gathers in flight (widened from r6's 4)
            for (int jj = 0; jj < cnt; jj += 8) {
                float w0 = __shfl(ex, jj);
                int s0 = __shfl(sj, jj);
                float w1 = (jj + 1 < cnt) ? __shfl(ex, jj + 1) : 0.f;
                int s1 = __shfl(sj, min(jj + 1, cnt - 1));
                float w2 = (jj + 2 < cnt) ? __shfl(ex, jj + 2) : 0.f;
                int s2 = __shfl(sj, min(jj + 2, cnt - 1));
                float w3 = (jj + 3 < cnt) ? __shfl(ex, jj + 3) : 0.f;
                int s3 = __shfl(sj, min(jj + 3, cnt - 1));
                float w4 = (jj + 4 < cnt) ? __shfl(ex, jj + 4) : 0.f;
                int s4 = __shfl(sj, min(jj + 4, cnt - 1));
                float w5 = (jj + 5 < cnt) ? __shfl(ex, jj + 5) : 0.f;
                int s5 = __shfl(sj, min(jj + 5, cnt - 1));
                float w6 = (jj + 6 < cnt) ? __shfl(ex, jj + 6) : 0.f;
                int s6 = __shfl(sj, min(jj + 6, cnt - 1));
                float w7 = (jj + 7 < cnt) ? __shfl(ex, jj + 7) : 0.f;
                int s7 = __shfl(sj, min(jj + 7, cnt - 1));
                float v0 = bf2f(h[(size_t)s0 * 64 + lane]);
                float v1 = bf2f(h[(size_t)s1 * 64 + lane]);
                float v2 = bf2f(h[(size_t)s2 * 64 + lane]);
                float v3 = bf2f(h[(size_t)s3 * 64 + lane]);
                float v4 = bf2f(h[(size_t)s4 * 64 + lane]);
                float v5 = bf2f(h[(size_t)s5 * 64 + lane]);
                float v6 = bf2f(h[(size_t)s6 * 64 + lane]);
                float v7 = bf2f(h[(size_t)s7 * 64 + lane]);
                acc = fmaf(w0, v0, acc);
                acc = fmaf(w1, v1, acc);
                acc = fmaf(w2, v2, acc);
                acc = fmaf(w3, v3, acc);
                acc = fmaf(w4, v4, acc);
                acc = fmaf(w5, v5, acc);
                acc = fmaf(w6, v6, acc);
                acc = fmaf(w7, v7, acc);
            }
        } else {
            const int half = lane >> 5;   // r6-verified 2-group split
            // 4 independent gathers in flight (widened from r6's 2)
            for (int jj = 0; jj < cnt; jj += 8) {
                int j2 = jj + half;
                int j3 = jj + 2 + half;
                int j4 = jj + 4 + half;
                int j5 = jj + 6 + half;
                float w0 = (j2 < cnt) ? __shfl(ex, j2) : 0.f;
                int s0 = __shfl(sj, min(j2, cnt - 1));
                float w1 = (j3 < cnt) ? __shfl(ex, j3) : 0.f;
                int s1 = __shfl(sj, min(j3, cnt - 1));
                float w2 = (j4 < cnt) ? __shfl(ex, j4) : 0.f;
                int s2 = __shfl(sj, min(j4, cnt - 1));
                float w3 = (j5 < cnt) ? __shfl(ex, j5) : 0.f;
                int s3 = __shfl(sj, min(j5, cnt - 1));
                float v0 = bf2f(h[(size_t)s0 * C + ch]);
                float v1 = bf2f(h[(size_t)s1 * C + ch]);
                float v2 = bf2f(h[(size_t)s2 * C + ch]);
                float v3 = bf2f(h[(size_t)s3 * C + ch]);
                acc = fmaf(w0, v0, acc);
                acc = fmaf(w1, v1, acc);
                acc = fmaf(w2, v2, acc);
                acc = fmaf(w3, v3, acc);
            }
        }
    }
    if (C == 32) {
        acc += __shfl_xor(acc, 32);
        if (lane < 32) agg[(size_t)dst * C + ch] = acc / l;
    } else {
        agg[(size_t)dst * C + ch] = acc / l;
    }
}

// ---------------------------------------------------------------------------
// GEMM2: hin = relu(agg1 + b1); h2[N,32](bf16) = hin[N,64] @ W[64,32]; alphas.
// ---------------------------------------------------------------------------
__global__ __launch_bounds__(256) void gemm2_kernel(
    const float* __restrict__ agg1, const void* __restrict__ b1,
    const u32* __restrict__ W32, const void* __restrict__ a_src,
    const void* __restrict__ a_dst, const int* __restrict__ flags,
    u16* __restrict__ h, float* __restrict__ as_, float* __restrict__ ad_)
{
    __shared__ __align__(16) float Wl[64 * 32];
    __shared__ __align__(16) float xs[64 * 68];
    const int tid = threadIdx.x;
    const int node0 = blockIdx.x * 64;
    const int bf = flags[0];

    if (bf) {
        for (int i = tid; i < 1024; i += 256) {
            u32 u = W32[i];
            *(float2*)&Wl[2 * i] = make_float2(__uint_as_float(u << 16),
                                               __uint_as_float(u & 0xFFFF0000u));
        }
    } else {
        for (int i = tid; i < 2048; i += 256) Wl[i] = __uint_as_float(W32[i]);
    }
    for (int i = tid; i < 64 * 64; i += 256) {
        int nl = i >> 6, k = i & 63;
        int n = node0 + nl;
        float v = 0.f;
        if (n < N_NODES) v = agg1[(size_t)n * 64 + k] + ldf(b1, k, bf);
        xs[nl * 68 + k] = fmaxf(v, 0.f);
    }
    __syncthreads();

    const int ch0 = (tid & 7) * 4;
    const int n0 = (tid >> 3) * 2;
    float acc0[4] = {0.f, 0.f, 0.f, 0.f}, acc1[4] = {0.f, 0.f, 0.f, 0.f};
    for (int k = 0; k < 64; k += 4) {
        float4 xa = *(const float4*)&xs[n0 * 68 + k];
        float4 xb = *(const float4*)&xs[(n0 + 1) * 68 + k];
        const float* xap = (const float*)&xa;
        const float* xbp = (const float*)&xb;
        #pragma unroll
        for (int kk = 0; kk < 4; ++kk) {
            float4 w = *(const float4*)&Wl[(k + kk) * 32 + ch0];
            float va = xap[kk], vb = xbp[kk];
            acc0[0] += va * w.x; acc0[1] += va * w.y; acc0[2] += va * w.z; acc0[3] += va * w.w;
            acc1[0] += vb * w.x; acc1[1] += vb * w.y; acc1[2] += vb * w.z; acc1[3] += vb * w.w;
        }
    }
    float ps0 = 0.f, ps1 = 0.f, pd0 = 0.f, pd1 = 0.f;
    #pragma unroll
    for (int q = 0; q < 4; ++q) {
        float asv = ldf(a_src, ch0 + q, bf);
        float adv = ldf(a_dst, ch0 + q, bf);
        ps0 += acc0[q] * asv; pd0 += acc0[q] * adv;
        ps1 += acc1[q] * asv; pd1 += acc1[q] * adv;
    }
    #pragma unroll
    for (int off = 1; off < 8; off <<= 1) {
        ps0 += __shfl_xor(ps0, off);
        pd0 += __shfl_xor(pd0, off);
        ps1 += __shfl_xor(ps1, off);
        pd1 += __shfl_xor(pd1, off);
    }
    int na = node0 + n0, nb = na + 1;
    if (na < N_NODES) {
        u32 p0 = (u32)f2bf(acc0[0]) | ((u32)f2bf(acc0[1]) << 16);
        u32 p1 = (u32)f2bf(acc0[2]) | ((u32)f2bf(acc0[3]) << 16);
        *(uint2*)&h[(size_t)na * 32 + ch0] = make_uint2(p0, p1);
        if ((tid & 7) == 0) { as_[na] = ps0; ad_[na] = pd0; }
    }
    if (nb < N_NODES) {
        u32 p0 = (u32)f2bf(acc1[0]) | ((u32)f2bf(acc1[1]) << 16);
        u32 p1 = (u32)f2bf(acc1[2]) | ((u32)f2bf(acc1[3]) << 16);
        *(uint2*)&h[(size_t)nb * 32 + ch0] = make_uint2(p0, p1);
        if ((tid & 7) == 0) { as_[nb] = ps1; ad_[nb] = pd1; }
    }
}

// Final: out = log_softmax(agg2 + b2) per row of 32, float32 store
__global__ __launch_bounds__(256) void lsm_kernel(
    const float* __restrict__ agg2, const void* __restrict__ b2,
    const int* __restrict__ flags, float* __restrict__ out)
{
    int gt = blockIdx.x * 256 + threadIdx.x;
    int n = gt >> 5, c = gt & 31;
    if (n >= N_NODES) return;
    float v = agg2[(size_t)n * 32 + c] + ldf(b2, c, flags[0]);
    float mx = v;
    #pragma unroll
    for (int off = 16; off > 0; off >>= 1) mx = fmaxf(mx, __shfl_xor(mx, off, 32));
    float ex = __expf(v - mx);
    float ss = ex;
    #pragma unroll
    for (int off = 16; off > 0; off >>= 1) ss += __shfl_xor(ss, off, 32);
    out[(size_t)n * 32 + c] = v - mx - __logf(ss);
}

// ---------------------------------------------------------------------------
extern "C" void kernel_launch(void* const* d_in, const int* in_sizes, int n_in,
                              void* d_out, int out_size, void* d_ws, size_t ws_size,
                              hipStream_t stream) {
    const float* x   = (const float*)d_in[0];
    const int* ei    = (const int*)d_in[1];
    const float* W1  = (const float*)d_in[2];
    const void* a_s1 = d_in[3];
    const void* a_d1 = d_in[4];
    const void* b1   = d_in[5];
    const u32* W2    = (const u32*)d_in[6];
    const void* a_s2 = d_in[7];
    const void* a_d2 = d_in[8];
    const void* b2   = d_in[9];
    float* out = (float*)d_out;

    // workspace carve-up (r6-verified layout; bbuf aliases agg2)
    char* base = (char*)d_ws;
    int* flags = (int*)base;
    u16* h     = (u16*)(base + 64);                           // N*64 bf16 (reused N*32)
    char* q = base + 64 + (size_t)N_NODES * 64 * 2;
    float* as1 = (float*)q; q += (size_t)N_NODES * 4;
    float* ad1 = (float*)q; q += (size_t)N_NODES * 4;
    float* as2 = (float*)q; q += (size_t)N_NODES * 4;
    float* ad2 = (float*)q; q += (size_t)N_NODES * 4;
    float* agg1 = (float*)q; q += (size_t)N_NODES * 64 * 4;
    float* agg2 = (float*)q; q += (size_t)N_NODES * 32 * 4;   // 12.8 MB
    u32*  bbuf  = (u32*)agg2;                                 // 8.03 MB alias
    int* rowptr = (int*)q;  q += (size_t)(N_NODES + 16) * 4;
    int* ssrc   = (int*)q;  q += (size_t)ET * 4;
    int* bcnt   = (int*)q;  q += 256 * 4;
    int* bbase  = (int*)q;  q += 256 * 4;
    hipMemsetAsync(bcnt, 0, 256 * 4, stream);

    detect_kernel<<<1, 64, 0, stream>>>((const u32*)x, ei, flags);

    // CSR by dst via 2-pass bucket sort (rowptr built in scatter)
    bin_kernel<<<(ET + BINCH - 1) / BINCH, 256, 0, stream>>>(ei, flags, bcnt, bbuf);
    bscan_kernel<<<1, 256, 0, stream>>>(bcnt, bbase);
    scatter_kernel<<<NBUCK, 256, 0, stream>>>(bcnt, bbase, bbuf, rowptr, ssrc);

    // layer 1
    gemm1_kernel<<<(N_NODES + 255) / 256, 256, 0, stream>>>(x, W1, a_s1, a_d1, flags, h, as1, ad1);
    gat_agg_kernel<64><<<(N_NODES + 3) / 4, 256, 0, stream>>>(rowptr, ssrc, as1, ad1, h, agg1);

    // layer 2
    gemm2_kernel<<<(N_NODES + 63) / 64, 256, 0, stream>>>(agg1, b1, W2, a_s2, a_d2, flags, h, as2, ad2);
    gat_agg_kernel<32><<<(N_NODES + 3) / 4, 256, 0, stream>>>(rowptr, ssrc, as2, ad2, h, agg2);

    // epilogue
    lsm_kernel<<<(N_NODES * 32 + 255) / 256, 256, 0, stream>>>(agg2, b2, flags, out);
}

// Round 10
// 374.198 us; speedup vs baseline: 2.9490x; 1.0079x over previous
//
#include <hip/hip_runtime.h>

#define N_NODES 100000
#define N_EDGES 1600000
#define ET (N_EDGES + N_NODES)
#define NEG_SLOPE 0.2f

// bucket sort params (round-6 verified)
#define BSHIFT 9
#define BW 512                                  // nodes per bucket
#define NBUCK ((N_NODES + BW - 1) / BW)         // 196
#define BCAP 10240
#define BINCH 4096                              // edges per bin block

typedef unsigned short u16;
typedef unsigned int u32;

__device__ __forceinline__ float bf2f(u16 v) {
    return __uint_as_float(((u32)v) << 16);
}
__device__ __forceinline__ u16 f2bf(float f) {
    u32 u = __float_as_uint(f);
    u32 r = (u + 0x7FFFu + ((u >> 16) & 1u)) >> 16;  // RNE
    return (u16)r;
}
__device__ __forceinline__ float lrelu(float x) { return x > 0.f ? x : NEG_SLOPE * x; }
__device__ __forceinline__ float ldf(const void* p, int i, int bf) {
    return bf ? bf2f(((const u16*)p)[i]) : ((const float*)p)[i];
}
// wave-uniform lane broadcast via v_readlane (no LDS pipe, no bpermute)
__device__ __forceinline__ float rl_f(float v, int l) {
    return __int_as_float(__builtin_amdgcn_readlane(__float_as_int(v), l));
}
__device__ __forceinline__ int rl_i(int v, int l) {
    return __builtin_amdgcn_readlane(v, l);
}
__device__ __forceinline__ int get_dst(const int* __restrict__ ei, int e, int ei64) {
    if (e < N_EDGES) return ei64 ? ei[2 * (N_EDGES + e)] : ei[N_EDGES + e];
    return e - N_EDGES;
}
__device__ __forceinline__ int get_src(const int* __restrict__ ei, int e, int ei64) {
    if (e < N_EDGES) return ei64 ? ei[2 * e] : ei[e];
    return e - N_EDGES;
}

// ---------------------------------------------------------------------------
__global__ void detect_kernel(const u32* __restrict__ x32, const int* __restrict__ ei,
                              int* __restrict__ flags) {
    int lane = threadIdx.x;  // 64
    u32 e = (x32[lane] >> 7) & 0xFFu;
    int ok = (e >= 96u && e <= 143u) ? 1 : 0;
    int cnt = (int)__popcll(__ballot(ok));
    int nz = (ei[2 * lane + 1] != 0) + (ei[2 * (lane + 64) + 1] != 0);
    #pragma unroll
    for (int off = 32; off > 0; off >>= 1) nz += __shfl_xor(nz, off);
    if (lane == 0) { flags[0] = (cnt >= 48) ? 1 : 0; flags[1] = (nz == 0) ? 1 : 0; }
}

// ---------------------------------------------------------------------------
// Pass 1: bin edges by dst>>9 into 196 buckets; code = (dst&511)<<17 | src.
// ---------------------------------------------------------------------------
__global__ __launch_bounds__(256) void bin_kernel(
    const int* __restrict__ ei, const int* __restrict__ flags,
    int* __restrict__ bcnt, u32* __restrict__ bbuf)
{
    __shared__ int hist[NBUCK];
    const int t = threadIdx.x;
    const int base = blockIdx.x * BINCH;
    const int ei64 = flags[1];
    for (int i = t; i < NBUCK; i += 256) hist[i] = 0;
    __syncthreads();
    for (int i = t; i < BINCH; i += 256) {
        int e = base + i;
        if (e >= ET) break;
        int d = get_dst(ei, e, ei64);
        atomicAdd(&hist[d >> BSHIFT], 1);
    }
    __syncthreads();
    for (int i = t; i < NBUCK; i += 256) {
        int c = hist[i];
        hist[i] = (c > 0) ? atomicAdd(&bcnt[i], c) : 0;
    }
    __syncthreads();
    for (int i = t; i < BINCH; i += 256) {
        int e = base + i;
        if (e >= ET) break;
        int d = get_dst(ei, e, ei64);
        int s = get_src(ei, e, ei64);
        int b = d >> BSHIFT;
        int pos = atomicAdd(&hist[b], 1);
        if (pos < BCAP)
            bbuf[(size_t)b * BCAP + pos] = ((u32)(d & (BW - 1)) << 17) | (u32)s;
    }
}

// exclusive scan of clamped bucket counts -> bbase[NBUCK+1]
__global__ __launch_bounds__(256) void bscan_kernel(
    const int* __restrict__ bcnt, int* __restrict__ bbase)
{
    __shared__ int sd[256];
    int t = threadIdx.x;
    int v = (t < NBUCK) ? min(bcnt[t], BCAP) : 0;
    sd[t] = v;
    __syncthreads();
    for (int off = 1; off < 256; off <<= 1) {
        int x = (t >= off) ? sd[t - off] : 0;
        __syncthreads();
        sd[t] += x;
        __syncthreads();
    }
    if (t < NBUCK) bbase[t] = sd[t] - v;
    if (t == NBUCK - 1) bbase[NBUCK] = sd[t];
}

// ---------------------------------------------------------------------------
// Pass 2: one block per bucket -> rowptr + dst-sorted ssrc.
// ---------------------------------------------------------------------------
__global__ __launch_bounds__(256) void scatter_kernel(
    const int* __restrict__ bcnt, const int* __restrict__ bbase,
    const u32* __restrict__ bbuf, int* __restrict__ rowptr, int* __restrict__ ssrc)
{
    __shared__ int hist[BW];
    __shared__ int cur[BW];
    __shared__ int wtot[4];
    __shared__ int lds_s[BCAP];
    const int t = threadIdx.x;
    const int b = blockIdx.x;
    const int cnt = min(bcnt[b], BCAP);
    const int base = bbase[b];
    const u32* mybuf = bbuf + (size_t)b * BCAP;

    hist[t] = 0; hist[t + 256] = 0;
    __syncthreads();
    for (int i = t; i < cnt; i += 256) {
        int ld = (int)(mybuf[i] >> 17);
        atomicAdd(&hist[ld], 1);
    }
    __syncthreads();
    int a0 = hist[2 * t], a1 = hist[2 * t + 1];
    int s = a0 + a1;
    int lane = t & 63, wid = t >> 6;
    int v = s;
    #pragma unroll
    for (int off = 1; off < 64; off <<= 1) {
        int n = __shfl_up(v, off);
        if (lane >= off) v += n;
    }
    if (lane == 63) wtot[wid] = v;
    __syncthreads();
    if (t == 0) {
        int acc = 0;
        #pragma unroll
        for (int w = 0; w < 4; ++w) { int tmp = wtot[w]; wtot[w] = acc; acc += tmp; }
    }
    __syncthreads();
    int excl_pair = v + wtot[wid] - s;
    cur[2 * t] = excl_pair;
    cur[2 * t + 1] = excl_pair + a0;
    __syncthreads();
    for (int li = t; li < BW; li += 256) {
        int g = b * BW + li;
        if (g < N_NODES) rowptr[g] = base + cur[li];
    }
    if (b == NBUCK - 1 && t == 0) rowptr[N_NODES] = bbase[NBUCK];
    __syncthreads();
    for (int i = t; i < cnt; i += 256) {
        u32 code = mybuf[i];
        int ld = (int)(code >> 17);
        int pos = atomicAdd(&cur[ld], 1);
        lds_s[pos] = (int)(code & 0x1FFFFu);
    }
    __syncthreads();
    for (int i = t; i < cnt; i += 256) ssrc[base + i] = lds_s[i];
}

// ---------------------------------------------------------------------------
// GEMM1: h[N,64](bf16) = x[N,128] @ W[128,64]; as_/ad_ score dots.
// ---------------------------------------------------------------------------
__global__ __launch_bounds__(256) void gemm1_kernel(
    const float* __restrict__ x, const float* __restrict__ W,
    const void* __restrict__ a_src, const void* __restrict__ a_dst,
    const int* __restrict__ flags,
    u16* __restrict__ h, float* __restrict__ as_, float* __restrict__ ad_)
{
    __shared__ float xs[256 * 33];   // 33.8 KB
    __shared__ float Wl[32 * 64];    // 8 KB
    const int t = threadIdx.x;
    const int node0 = blockIdx.x * 256;
    const int bf = flags[0];
    const int ng = t >> 3;
    const int cg = t & 7;

    float acc[8][8];
    #pragma unroll
    for (int i = 0; i < 8; ++i)
        #pragma unroll
        for (int j = 0; j < 8; ++j) acc[i][j] = 0.f;

    for (int kc = 0; kc < 4; ++kc) {
        const int kb = kc * 32;
        const int c4 = t & 7;
        #pragma unroll
        for (int p = 0; p < 8; ++p) {
            int row = (t >> 3) + p * 32;
            int n = node0 + row;
            float4 vv = make_float4(0.f, 0.f, 0.f, 0.f);
            if (n < N_NODES) {
                if (!bf) {
                    vv = *(const float4*)(x + (size_t)n * 128 + kb + c4 * 4);
                } else {
                    const u16* xh = (const u16*)x;
                    vv.x = bf2f(xh[(size_t)n * 128 + kb + c4 * 4 + 0]);
                    vv.y = bf2f(xh[(size_t)n * 128 + kb + c4 * 4 + 1]);
                    vv.z = bf2f(xh[(size_t)n * 128 + kb + c4 * 4 + 2]);
                    vv.w = bf2f(xh[(size_t)n * 128 + kb + c4 * 4 + 3]);
                }
            }
            float* dstp = &xs[row * 33 + c4 * 4];
            dstp[0] = vv.x; dstp[1] = vv.y; dstp[2] = vv.z; dstp[3] = vv.w;
        }
        if (!bf) {
            #pragma unroll
            for (int qq = 0; qq < 2; ++qq) {
                int f4 = t * 2 + qq;
                ((float4*)Wl)[f4] = ((const float4*)(W + (size_t)kb * 64))[f4];
            }
        } else {
            const u16* Wh = (const u16*)W;
            for (int i = t; i < 2048; i += 256) Wl[i] = bf2f(Wh[(size_t)kb * 64 + i]);
        }
        __syncthreads();

        for (int kk = 0; kk < 32; ++kk) {
            float xr[8];
            #pragma unroll
            for (int i = 0; i < 8; ++i) xr[i] = xs[(ng * 8 + i) * 33 + kk];
            float4 w0 = *(const float4*)&Wl[kk * 64 + cg * 8];
            float4 w1 = *(const float4*)&Wl[kk * 64 + cg * 8 + 4];
            const float wr[8] = {w0.x, w0.y, w0.z, w0.w, w1.x, w1.y, w1.z, w1.w};
            #pragma unroll
            for (int i = 0; i < 8; ++i)
                #pragma unroll
                for (int j = 0; j < 8; ++j)
                    acc[i][j] = fmaf(xr[i], wr[j], acc[i][j]);
        }
        __syncthreads();
    }

    float av[8], dv[8];
    #pragma unroll
    for (int j = 0; j < 8; ++j) {
        av[j] = ldf(a_src, cg * 8 + j, bf);
        dv[j] = ldf(a_dst, cg * 8 + j, bf);
    }
    #pragma unroll
    for (int i = 0; i < 8; ++i) {
        int n = node0 + ng * 8 + i;
        float ps = 0.f, pd = 0.f;
        #pragma unroll
        for (int j = 0; j < 8; ++j) { ps += acc[i][j] * av[j]; pd += acc[i][j] * dv[j]; }
        #pragma unroll
        for (int off = 1; off < 8; off <<= 1) {
            ps += __shfl_xor(ps, off);
            pd += __shfl_xor(pd, off);
        }
        if (n < N_NODES) {
            uint4 hv;
            hv.x = (u32)f2bf(acc[i][0]) | ((u32)f2bf(acc[i][1]) << 16);
            hv.y = (u32)f2bf(acc[i][2]) | ((u32)f2bf(acc[i][3]) << 16);
            hv.z = (u32)f2bf(acc[i][4]) | ((u32)f2bf(acc[i][5]) << 16);
            hv.w = (u32)f2bf(acc[i][6]) | ((u32)f2bf(acc[i][7]) << 16);
            *(uint4*)&h[(size_t)n * 64 + cg * 8] = hv;
            if (cg == 0) { as_[n] = ps; ad_[n] = pd; }
        }
    }
}

// ---------------------------------------------------------------------------
// Layer-1 aggregation, C=64. One wave per dst; lane = channel (r6-validated
// mapping). Edge broadcasts via v_readlane (wave-uniform index): no bpermute,
// no guards in the full-group loop.
// ---------------------------------------------------------------------------
__global__ __launch_bounds__(256) void gat_agg64_kernel(
    const int* __restrict__ rowptr, const int* __restrict__ ssrc,
    const float* __restrict__ as_, const float* __restrict__ ad_,
    const u16* __restrict__ h, float* __restrict__ agg)
{
    const int lane = threadIdx.x & 63;
    const int dst = blockIdx.x * 4 + (threadIdx.x >> 6);
    if (dst >= N_NODES) return;
    const int beg = rowptr[dst], end = rowptr[dst + 1];
    const float add = ad_[dst];
    const u16* __restrict__ hl = h + lane;

    float m = -1e30f, l = 0.f, acc = 0.f;
    for (int base = beg; base < end; base += 64) {
        int j = base + lane;
        int sj = 0;
        float sc = -1e30f;
        if (j < end) { sj = ssrc[j]; sc = lrelu(as_[sj] + add); }
        float cm = sc;
        #pragma unroll
        for (int off = 32; off > 0; off >>= 1) cm = fmaxf(cm, __shfl_xor(cm, off));
        float nm = fmaxf(m, cm);
        float scale = __expf(m - nm);
        float ex = (j < end) ? __expf(sc - nm) : 0.f;
        float cs = ex;
        #pragma unroll
        for (int off = 32; off > 0; off >>= 1) cs += __shfl_xor(cs, off);
        l = l * scale + cs;
        acc *= scale;
        m = nm;

        const int cnt = min(64, end - base);
        int jj = 0;
        for (; jj + 8 <= cnt; jj += 8) {
            #pragma unroll
            for (int k = 0; k < 8; ++k) {
                float w = rl_f(ex, jj + k);
                int   s = rl_i(sj, jj + k);
                acc = fmaf(w, bf2f(hl[(size_t)s * 64]), acc);
            }
        }
        for (; jj < cnt; ++jj) {
            float w = rl_f(ex, jj);
            int   s = rl_i(sj, jj);
            acc = fmaf(w, bf2f(hl[(size_t)s * 64]), acc);
        }
    }
    agg[(size_t)dst * 64 + lane] = acc / l;
}

// ---------------------------------------------------------------------------
// Layer-2 aggregation, C=32, r6-validated half-split (2 edges/step) with
// readlane broadcasts; fused bias + log_softmax -> out (f32).
// ---------------------------------------------------------------------------
__global__ __launch_bounds__(256) void gat_agg32_lsm_kernel(
    const int* __restrict__ rowptr, const int* __restrict__ ssrc,
    const float* __restrict__ as_, const float* __restrict__ ad_,
    const u16* __restrict__ h, const void* __restrict__ b2,
    const int* __restrict__ flags, float* __restrict__ out)
{
    const int lane = threadIdx.x & 63;
    const int dst = blockIdx.x * 4 + (threadIdx.x >> 6);
    if (dst >= N_NODES) return;
    const int beg = rowptr[dst], end = rowptr[dst + 1];
    const float add = ad_[dst];
    const int ch = lane & 31;
    const int half = lane >> 5;
    const int bf = flags[0];
    const u16* __restrict__ hl = h + ch;

    float m = -1e30f, l = 0.f, acc = 0.f;
    for (int base = beg; base < end; base += 64) {
        int j = base + lane;
        int sj = 0;
        float sc = -1e30f;
        if (j < end) { sj = ssrc[j]; sc = lrelu(as_[sj] + add); }
        float cm = sc;
        #pragma unroll
        for (int off = 32; off > 0; off >>= 1) cm = fmaxf(cm, __shfl_xor(cm, off));
        float nm = fmaxf(m, cm);
        float scale = __expf(m - nm);
        float ex = (j < end) ? __expf(sc - nm) : 0.f;
        float cs = ex;
        #pragma unroll
        for (int off = 32; off > 0; off >>= 1) cs += __shfl_xor(cs, off);
        l = l * scale + cs;
        acc *= scale;
        m = nm;

        const int cnt = min(64, end - base);
        int jj = 0;
        for (; jj + 8 <= cnt; jj += 8) {
            #pragma unroll
            for (int k = 0; k < 8; k += 2) {
                float wA = rl_f(ex, jj + k), wB = rl_f(ex, jj + k + 1);
                int   sA = rl_i(sj, jj + k), sB = rl_i(sj, jj + k + 1);
                float w = half ? wB : wA;
                int   s = half ? sB : sA;
                acc = fmaf(w, bf2f(hl[(size_t)s * 32]), acc);
            }
        }
        for (; jj + 2 <= cnt; jj += 2) {
            float wA = rl_f(ex, jj), wB = rl_f(ex, jj + 1);
            int   sA = rl_i(sj, jj), sB = rl_i(sj, jj + 1);
            float w = half ? wB : wA;
            int   s = half ? sB : sA;
            acc = fmaf(w, bf2f(hl[(size_t)s * 32]), acc);
        }
        if (jj < cnt) {   // odd leftover: only half==0 contributes
            float wA = rl_f(ex, jj);
            int   sA = rl_i(sj, jj);
            float w = half ? 0.f : wA;
            acc = fmaf(w, bf2f(hl[(size_t)sA * 32]), acc);
        }
    }
    acc += __shfl_xor(acc, 32);   // combine the two edge streams (r6-validated)

    // fused bias + log_softmax over 32 channels (xor stays within each half)
    float v = acc / l + ldf(b2, ch, bf);
    float mx = v;
    #pragma unroll
    for (int off = 1; off < 32; off <<= 1) mx = fmaxf(mx, __shfl_xor(mx, off));
    float e = __expf(v - mx);
    float ss = e;
    #pragma unroll
    for (int off = 1; off < 32; off <<= 1) ss += __shfl_xor(ss, off);
    float o = v - mx - __logf(ss);
    if (lane < 32) out[(size_t)dst * 32 + ch] = o;
}

// ---------------------------------------------------------------------------
// GEMM2: hin = relu(agg1 + b1); h2[N,32](bf16) = hin[N,64] @ W[64,32]; alphas.
// ---------------------------------------------------------------------------
__global__ __launch_bounds__(256) void gemm2_kernel(
    const float* __restrict__ agg1, const void* __restrict__ b1,
    const u32* __restrict__ W32, const void* __restrict__ a_src,
    const void* __restrict__ a_dst, const int* __restrict__ flags,
    u16* __restrict__ h, float* __restrict__ as_, float* __restrict__ ad_)
{
    __shared__ __align__(16) float Wl[64 * 32];
    __shared__ __align__(16) float xs[64 * 68];
    const int tid = threadIdx.x;
    const int node0 = blockIdx.x * 64;
    const int bf = flags[0];

    if (bf) {
        for (int i = tid; i < 1024; i += 256) {
            u32 u = W32[i];
            *(float2*)&Wl[2 * i] = make_float2(__uint_as_float(u << 16),
                                               __uint_as_float(u & 0xFFFF0000u));
        }
    } else {
        for (int i = tid; i < 2048; i += 256) Wl[i] = __uint_as_float(W32[i]);
    }
    for (int i = tid; i < 64 * 64; i += 256) {
        int nl = i >> 6, k = i & 63;
        int n = node0 + nl;
        float v = 0.f;
        if (n < N_NODES) v = agg1[(size_t)n * 64 + k] + ldf(b1, k, bf);
        xs[nl * 68 + k] = fmaxf(v, 0.f);
    }
    __syncthreads();

    const int ch0 = (tid & 7) * 4;
    const int n0 = (tid >> 3) * 2;
    float acc0[4] = {0.f, 0.f, 0.f, 0.f}, acc1[4] = {0.f, 0.f, 0.f, 0.f};
    for (int k = 0; k < 64; k += 4) {
        float4 xa = *(const float4*)&xs[n0 * 68 + k];
        float4 xb = *(const float4*)&xs[(n0 + 1) * 68 + k];
        const float* xap = (const float*)&xa;
        const float* xbp = (const float*)&xb;
        #pragma unroll
        for (int kk = 0; kk < 4; ++kk) {
            float4 w = *(const float4*)&Wl[(k + kk) * 32 + ch0];
            float va = xap[kk], vb = xbp[kk];
            acc0[0] += va * w.x; acc0[1] += va * w.y; acc0[2] += va * w.z; acc0[3] += va * w.w;
            acc1[0] += vb * w.x; acc1[1] += vb * w.y; acc1[2] += vb * w.z; acc1[3] += vb * w.w;
        }
    }
    float ps0 = 0.f, ps1 = 0.f, pd0 = 0.f, pd1 = 0.f;
    #pragma unroll
    for (int q = 0; q < 4; ++q) {
        float asv = ldf(a_src, ch0 + q, bf);
        float adv = ldf(a_dst, ch0 + q, bf);
        ps0 += acc0[q] * asv; pd0 += acc0[q] * adv;
        ps1 += acc1[q] * asv; pd1 += acc1[q] * adv;
    }
    #pragma unroll
    for (int off = 1; off < 8; off <<= 1) {
        ps0 += __shfl_xor(ps0, off);
        pd0 += __shfl_xor(pd0, off);
        ps1 += __shfl_xor(ps1, off);
        pd1 += __shfl_xor(pd1, off);
    }
    int na = node0 + n0, nb = na + 1;
    if (na < N_NODES) {
        u32 p0 = (u32)f2bf(acc0[0]) | ((u32)f2bf(acc0[1]) << 16);
        u32 p1 = (u32)f2bf(acc0[2]) | ((u32)f2bf(acc0[3]) << 16);
        *(uint2*)&h[(size_t)na * 32 + ch0] = make_uint2(p0, p1);
        if ((tid & 7) == 0) { as_[na] = ps0; ad_[na] = pd0; }
    }
    if (nb < N_NODES) {
        u32 p0 = (u32)f2bf(acc1[0]) | ((u32)f2bf(acc1[1]) << 16);
        u32 p1 = (u32)f2bf(acc1[2]) | ((u32)f2bf(acc1[3]) << 16);
        *(uint2*)&h[(size_t)nb * 32 + ch0] = make_uint2(p0, p1);
        if ((tid & 7) == 0) { as_[nb] = ps1; ad_[nb] = pd1; }
    }
}

// ---------------------------------------------------------------------------
extern "C" void kernel_launch(void* const* d_in, const int* in_sizes, int n_in,
                              void* d_out, int out_size, void* d_ws, size_t ws_size,
                              hipStream_t stream) {
    const float* x   = (const float*)d_in[0];
    const int* ei    = (const int*)d_in[1];
    const float* W1  = (const float*)d_in[2];
    const void* a_s1 = d_in[3];
    const void* a_d1 = d_in[4];
    const void* b1   = d_in[5];
    const u32* W2    = (const u32*)d_in[6];
    const void* a_s2 = d_in[7];
    const void* a_d2 = d_in[8];
    const void* b2   = d_in[9];
    float* out = (float*)d_out;

    // workspace carve-up (~55 MB)
    char* base = (char*)d_ws;
    int* flags = (int*)base;
    u16* h     = (u16*)(base + 64);                           // N*64 bf16 (reused N*32)
    char* q = base + 64 + (size_t)N_NODES * 64 * 2;
    float* as1 = (float*)q; q += (size_t)N_NODES * 4;
    float* ad1 = (float*)q; q += (size_t)N_NODES * 4;
    float* as2 = (float*)q; q += (size_t)N_NODES * 4;
    float* ad2 = (float*)q; q += (size_t)N_NODES * 4;
    float* agg1 = (float*)q; q += (size_t)N_NODES * 64 * 4;
    u32*  bbuf  = (u32*)q;  q += (size_t)NBUCK * BCAP * 4;    // 8.03 MB
    int* rowptr = (int*)q;  q += (size_t)(N_NODES + 16) * 4;
    int* ssrc   = (int*)q;  q += (size_t)ET * 4;
    int* bcnt   = (int*)q;  q += 256 * 4;
    int* bbase  = (int*)q;  q += 256 * 4;
    hipMemsetAsync(bcnt, 0, 256 * 4, stream);

    detect_kernel<<<1, 64, 0, stream>>>((const u32*)x, ei, flags);

    // CSR by dst via 2-pass bucket sort (rowptr built in scatter)
    bin_kernel<<<(ET + BINCH - 1) / BINCH, 256, 0, stream>>>(ei, flags, bcnt, bbuf);
    bscan_kernel<<<1, 256, 0, stream>>>(bcnt, bbase);
    scatter_kernel<<<NBUCK, 256, 0, stream>>>(bcnt, bbase, bbuf, rowptr, ssrc);

    // layer 1
    gemm1_kernel<<<(N_NODES + 255) / 256, 256, 0, stream>>>(x, W1, a_s1, a_d1, flags, h, as1, ad1);
    gat_agg64_kernel<<<(N_NODES + 3) / 4, 256, 0, stream>>>(rowptr, ssrc, as1, ad1, h, agg1);

    // layer 2 (lsm fused; writes d_out directly)
    gemm2_kernel<<<(N_NODES + 63) / 64, 256, 0, stream>>>(agg1, b1, W2, a_s2, a_d2, flags, h, as2, ad2);
    gat_agg32_lsm_kernel<<<(N_NODES + 3) / 4, 256, 0, stream>>>(rowptr, ssrc, as2, ad2, h, b2, flags, out);
}

// Round 11
// 363.427 us; speedup vs baseline: 3.0364x; 1.0296x over previous
//
#include <hip/hip_runtime.h>

#define N_NODES 100000
#define N_EDGES 1600000
#define ET (N_EDGES + N_NODES)
#define NEG_SLOPE 0.2f

// bucket sort params
#define BSHIFT 9
#define BW 512                                  // nodes per bucket
#define NBUCK ((N_NODES + BW - 1) / BW)         // 196
#define BCAP 10240
#define BINCH 2048                              // edges per bin block

typedef unsigned short u16;
typedef unsigned int u32;

__device__ __forceinline__ float bf2f(u16 v) {
    return __uint_as_float(((u32)v) << 16);
}
__device__ __forceinline__ u16 f2bf(float f) {
    u32 u = __float_as_uint(f);
    u32 r = (u + 0x7FFFu + ((u >> 16) & 1u)) >> 16;  // RNE
    return (u16)r;
}
__device__ __forceinline__ float lrelu(float x) { return x > 0.f ? x : NEG_SLOPE * x; }
__device__ __forceinline__ float ldf(const void* p, int i, int bf) {
    return bf ? bf2f(((const u16*)p)[i]) : ((const float*)p)[i];
}
// wave-uniform lane broadcast via v_readlane
__device__ __forceinline__ float rl_f(float v, int l) {
    return __int_as_float(__builtin_amdgcn_readlane(__float_as_int(v), l));
}
__device__ __forceinline__ int rl_i(int v, int l) {
    return __builtin_amdgcn_readlane(v, l);
}
__device__ __forceinline__ int get_dst(const int* __restrict__ ei, int e, int ei64) {
    if (e < N_EDGES) return ei64 ? ei[2 * (N_EDGES + e)] : ei[N_EDGES + e];
    return e - N_EDGES;
}
__device__ __forceinline__ int get_src(const int* __restrict__ ei, int e, int ei64) {
    if (e < N_EDGES) return ei64 ? ei[2 * e] : ei[e];
    return e - N_EDGES;
}

// ---------------------------------------------------------------------------
// Detect input storage + zero bcnt (memset dispatch folded in).
// ---------------------------------------------------------------------------
__global__ void detect_kernel(const u32* __restrict__ x32, const int* __restrict__ ei,
                              int* __restrict__ flags, int* __restrict__ bcnt) {
    int lane = threadIdx.x;  // 64
    for (int i = lane; i < 256; i += 64) bcnt[i] = 0;
    u32 e = (x32[lane] >> 7) & 0xFFu;
    int ok = (e >= 96u && e <= 143u) ? 1 : 0;
    int cnt = (int)__popcll(__ballot(ok));
    int nz = (ei[2 * lane + 1] != 0) + (ei[2 * (lane + 64) + 1] != 0);
    #pragma unroll
    for (int off = 32; off > 0; off >>= 1) nz += __shfl_xor(nz, off);
    if (lane == 0) { flags[0] = (cnt >= 48) ? 1 : 0; flags[1] = (nz == 0) ? 1 : 0; }
}

// ---------------------------------------------------------------------------
// Pass 1: bin edges by dst>>9 into 196 buckets; code = (dst&511)<<17 | src.
// ---------------------------------------------------------------------------
__global__ __launch_bounds__(256) void bin_kernel(
    const int* __restrict__ ei, const int* __restrict__ flags,
    int* __restrict__ bcnt, u32* __restrict__ bbuf)
{
    __shared__ int hist[NBUCK];
    const int t = threadIdx.x;
    const int base = blockIdx.x * BINCH;
    const int ei64 = flags[1];
    for (int i = t; i < NBUCK; i += 256) hist[i] = 0;
    __syncthreads();
    for (int i = t; i < BINCH; i += 256) {
        int e = base + i;
        if (e >= ET) break;
        int d = get_dst(ei, e, ei64);
        atomicAdd(&hist[d >> BSHIFT], 1);
    }
    __syncthreads();
    for (int i = t; i < NBUCK; i += 256) {
        int c = hist[i];
        hist[i] = (c > 0) ? atomicAdd(&bcnt[i], c) : 0;
    }
    __syncthreads();
    for (int i = t; i < BINCH; i += 256) {
        int e = base + i;
        if (e >= ET) break;
        int d = get_dst(ei, e, ei64);
        int s = get_src(ei, e, ei64);
        int b = d >> BSHIFT;
        int pos = atomicAdd(&hist[b], 1);
        if (pos < BCAP)
            bbuf[(size_t)b * BCAP + pos] = ((u32)(d & (BW - 1)) << 17) | (u32)s;
    }
}

// exclusive scan of clamped bucket counts -> bbase[NBUCK+1]
__global__ __launch_bounds__(256) void bscan_kernel(
    const int* __restrict__ bcnt, int* __restrict__ bbase)
{
    __shared__ int sd[256];
    int t = threadIdx.x;
    int v = (t < NBUCK) ? min(bcnt[t], BCAP) : 0;
    sd[t] = v;
    __syncthreads();
    for (int off = 1; off < 256; off <<= 1) {
        int x = (t >= off) ? sd[t - off] : 0;
        __syncthreads();
        sd[t] += x;
        __syncthreads();
    }
    if (t < NBUCK) bbase[t] = sd[t] - v;
    if (t == NBUCK - 1) bbase[NBUCK] = sd[t];
}

// ---------------------------------------------------------------------------
// Pass 2: one block (1024 threads) per bucket -> rowptr + dst-sorted ssrc.
// Same r6 phase structure; loops 4x wider, scan gated to t<256.
// ---------------------------------------------------------------------------
__global__ __launch_bounds__(1024) void scatter_kernel(
    const int* __restrict__ bcnt, const int* __restrict__ bbase,
    const u32* __restrict__ bbuf, int* __restrict__ rowptr, int* __restrict__ ssrc)
{
    __shared__ int hist[BW];
    __shared__ int cur[BW];
    __shared__ int wtot[4];
    __shared__ int lds_s[BCAP];
    const int t = threadIdx.x;
    const int b = blockIdx.x;
    const int cnt = min(bcnt[b], BCAP);
    const int base = bbase[b];
    const u32* mybuf = bbuf + (size_t)b * BCAP;

    if (t < BW) hist[t] = 0;
    __syncthreads();
    for (int i = t; i < cnt; i += 1024) atomicAdd(&hist[(int)(mybuf[i] >> 17)], 1);
    __syncthreads();
    int a0 = 0, a1 = 0, s = 0, v = 0;
    const int lane = t & 63, wid = t >> 6;
    if (t < 256) {
        a0 = hist[2 * t]; a1 = hist[2 * t + 1];
        s = a0 + a1;
        v = s;
        #pragma unroll
        for (int off = 1; off < 64; off <<= 1) {
            int n = __shfl_up(v, off);
            if (lane >= off) v += n;
        }
        if (lane == 63) wtot[wid] = v;
    }
    __syncthreads();
    if (t == 0) {
        int acc = 0;
        #pragma unroll
        for (int w = 0; w < 4; ++w) { int tmp = wtot[w]; wtot[w] = acc; acc += tmp; }
    }
    __syncthreads();
    if (t < 256) {
        int excl = v + wtot[wid] - s;
        cur[2 * t] = excl;
        cur[2 * t + 1] = excl + a0;
    }
    __syncthreads();
    if (t < BW) {
        int g = b * BW + t;
        if (g < N_NODES) rowptr[g] = base + cur[t];
    }
    if (b == NBUCK - 1 && t == 0) rowptr[N_NODES] = bbase[NBUCK];
    __syncthreads();
    for (int i = t; i < cnt; i += 1024) {
        u32 code = mybuf[i];
        int pos = atomicAdd(&cur[(int)(code >> 17)], 1);
        lds_s[pos] = (int)(code & 0x1FFFFu);
    }
    __syncthreads();
    for (int i = t; i < cnt; i += 1024) ssrc[base + i] = lds_s[i];
}

// ---------------------------------------------------------------------------
// GEMM1: h[N,64](bf16) = x[N,128] @ W[128,64]; as_/ad_ score dots.
// ---------------------------------------------------------------------------
__global__ __launch_bounds__(256) void gemm1_kernel(
    const float* __restrict__ x, const float* __restrict__ W,
    const void* __restrict__ a_src, const void* __restrict__ a_dst,
    const int* __restrict__ flags,
    u16* __restrict__ h, float* __restrict__ as_, float* __restrict__ ad_)
{
    __shared__ float xs[256 * 33];   // 33.8 KB
    __shared__ float Wl[32 * 64];    // 8 KB
    const int t = threadIdx.x;
    const int node0 = blockIdx.x * 256;
    const int bf = flags[0];
    const int ng = t >> 3;
    const int cg = t & 7;

    float acc[8][8];
    #pragma unroll
    for (int i = 0; i < 8; ++i)
        #pragma unroll
        for (int j = 0; j < 8; ++j) acc[i][j] = 0.f;

    for (int kc = 0; kc < 4; ++kc) {
        const int kb = kc * 32;
        const int c4 = t & 7;
        #pragma unroll
        for (int p = 0; p < 8; ++p) {
            int row = (t >> 3) + p * 32;
            int n = node0 + row;
            float4 vv = make_float4(0.f, 0.f, 0.f, 0.f);
            if (n < N_NODES) {
                if (!bf) {
                    vv = *(const float4*)(x + (size_t)n * 128 + kb + c4 * 4);
                } else {
                    const u16* xh = (const u16*)x;
                    vv.x = bf2f(xh[(size_t)n * 128 + kb + c4 * 4 + 0]);
                    vv.y = bf2f(xh[(size_t)n * 128 + kb + c4 * 4 + 1]);
                    vv.z = bf2f(xh[(size_t)n * 128 + kb + c4 * 4 + 2]);
                    vv.w = bf2f(xh[(size_t)n * 128 + kb + c4 * 4 + 3]);
                }
            }
            float* dstp = &xs[row * 33 + c4 * 4];
            dstp[0] = vv.x; dstp[1] = vv.y; dstp[2] = vv.z; dstp[3] = vv.w;
        }
        if (!bf) {
            #pragma unroll
            for (int qq = 0; qq < 2; ++qq) {
                int f4 = t * 2 + qq;
                ((float4*)Wl)[f4] = ((const float4*)(W + (size_t)kb * 64))[f4];
            }
        } else {
            const u16* Wh = (const u16*)W;
            for (int i = t; i < 2048; i += 256) Wl[i] = bf2f(Wh[(size_t)kb * 64 + i]);
        }
        __syncthreads();

        for (int kk = 0; kk < 32; ++kk) {
            float xr[8];
            #pragma unroll
            for (int i = 0; i < 8; ++i) xr[i] = xs[(ng * 8 + i) * 33 + kk];
            float4 w0 = *(const float4*)&Wl[kk * 64 + cg * 8];
            float4 w1 = *(const float4*)&Wl[kk * 64 + cg * 8 + 4];
            const float wr[8] = {w0.x, w0.y, w0.z, w0.w, w1.x, w1.y, w1.z, w1.w};
            #pragma unroll
            for (int i = 0; i < 8; ++i)
                #pragma unroll
                for (int j = 0; j < 8; ++j)
                    acc[i][j] = fmaf(xr[i], wr[j], acc[i][j]);
        }
        __syncthreads();
    }

    float av[8], dv[8];
    #pragma unroll
    for (int j = 0; j < 8; ++j) {
        av[j] = ldf(a_src, cg * 8 + j, bf);
        dv[j] = ldf(a_dst, cg * 8 + j, bf);
    }
    #pragma unroll
    for (int i = 0; i < 8; ++i) {
        int n = node0 + ng * 8 + i;
        float ps = 0.f, pd = 0.f;
        #pragma unroll
        for (int j = 0; j < 8; ++j) { ps += acc[i][j] * av[j]; pd += acc[i][j] * dv[j]; }
        #pragma unroll
        for (int off = 1; off < 8; off <<= 1) {
            ps += __shfl_xor(ps, off);
            pd += __shfl_xor(pd, off);
        }
        if (n < N_NODES) {
            uint4 hv;
            hv.x = (u32)f2bf(acc[i][0]) | ((u32)f2bf(acc[i][1]) << 16);
            hv.y = (u32)f2bf(acc[i][2]) | ((u32)f2bf(acc[i][3]) << 16);
            hv.z = (u32)f2bf(acc[i][4]) | ((u32)f2bf(acc[i][5]) << 16);
            hv.w = (u32)f2bf(acc[i][6]) | ((u32)f2bf(acc[i][7]) << 16);
            *(uint4*)&h[(size_t)n * 64 + cg * 8] = hv;
            if (cg == 0) { as_[n] = ps; ad_[n] = pd; }
        }
    }
}

// ---------------------------------------------------------------------------
// Layer-1 aggregation, C=64. One wave per dst. Half-split u32 gather:
// 2 edges per load instruction (r9-validated select pattern), lane covers
// channels {2*hw, 2*hw+1}; combine via validated shfl_xor(,32).
// ---------------------------------------------------------------------------
__global__ __launch_bounds__(256) void gat_agg64_kernel(
    const int* __restrict__ rowptr, const int* __restrict__ ssrc,
    const float* __restrict__ as_, const float* __restrict__ ad_,
    const u16* __restrict__ h, float* __restrict__ agg)
{
    const int lane = threadIdx.x & 63;
    const int dst = blockIdx.x * 4 + (threadIdx.x >> 6);
    if (dst >= N_NODES) return;
    const int beg = rowptr[dst], end = rowptr[dst + 1];
    const float add = ad_[dst];
    const int half = lane >> 5;
    const int hw = lane & 31;                     // u32 index within 128-B row
    const u32* __restrict__ h32 = (const u32*)h;

    float m = -1e30f, l = 0.f, acc0 = 0.f, acc1 = 0.f;
    for (int base = beg; base < end; base += 64) {
        int j = base + lane;
        int sj = 0;
        float sc = -1e30f;
        if (j < end) { sj = ssrc[j]; sc = lrelu(as_[sj] + add); }
        float cm = sc;
        #pragma unroll
        for (int off = 32; off > 0; off >>= 1) cm = fmaxf(cm, __shfl_xor(cm, off));
        float nm = fmaxf(m, cm);
        float scale = __expf(m - nm);
        float ex = (j < end) ? __expf(sc - nm) : 0.f;
        float cs = ex;
        #pragma unroll
        for (int off = 32; off > 0; off >>= 1) cs += __shfl_xor(cs, off);
        l = l * scale + cs;
        acc0 *= scale; acc1 *= scale;
        m = nm;

        const int cnt = min(64, end - base);
        int jj = 0;
        for (; jj + 8 <= cnt; jj += 8) {
            #pragma unroll
            for (int k = 0; k < 8; k += 2) {
                float wA = rl_f(ex, jj + k), wB = rl_f(ex, jj + k + 1);
                int   sA = rl_i(sj, jj + k), sB = rl_i(sj, jj + k + 1);
                float w = half ? wB : wA;
                int   s = half ? sB : sA;
                u32 qv = h32[(size_t)s * 32 + hw];
                acc0 = fmaf(w, __uint_as_float(qv << 16), acc0);
                acc1 = fmaf(w, __uint_as_float(qv & 0xFFFF0000u), acc1);
            }
        }
        for (; jj + 2 <= cnt; jj += 2) {
            float wA = rl_f(ex, jj), wB = rl_f(ex, jj + 1);
            int   sA = rl_i(sj, jj), sB = rl_i(sj, jj + 1);
            float w = half ? wB : wA;
            int   s = half ? sB : sA;
            u32 qv = h32[(size_t)s * 32 + hw];
            acc0 = fmaf(w, __uint_as_float(qv << 16), acc0);
            acc1 = fmaf(w, __uint_as_float(qv & 0xFFFF0000u), acc1);
        }
        if (jj < cnt) {   // odd leftover: only half==0 contributes
            float wA = rl_f(ex, jj);
            int   sA = rl_i(sj, jj);
            float w = half ? 0.f : wA;
            u32 qv = h32[(size_t)sA * 32 + hw];
            acc0 = fmaf(w, __uint_as_float(qv << 16), acc0);
            acc1 = fmaf(w, __uint_as_float(qv & 0xFFFF0000u), acc1);
        }
    }
    acc0 += __shfl_xor(acc0, 32);
    acc1 += __shfl_xor(acc1, 32);
    if (lane < 32) {
        float inv = 1.f / l;
        *(float2*)&agg[(size_t)dst * 64 + 2 * hw] = make_float2(acc0 * inv, acc1 * inv);
    }
}

// ---------------------------------------------------------------------------
// Layer-2 aggregation, C=32, quarter-split u32 gather (4 edges per load
// instruction; readlane broadcasts + cndmask selects only), fused bias +
// log_softmax -> out (f32).
// ---------------------------------------------------------------------------
__global__ __launch_bounds__(256) void gat_agg32_lsm_kernel(
    const int* __restrict__ rowptr, const int* __restrict__ ssrc,
    const float* __restrict__ as_, const float* __restrict__ ad_,
    const u16* __restrict__ h, const void* __restrict__ b2,
    const int* __restrict__ flags, float* __restrict__ out)
{
    const int lane = threadIdx.x & 63;
    const int dst = blockIdx.x * 4 + (threadIdx.x >> 6);
    if (dst >= N_NODES) return;
    const int beg = rowptr[dst], end = rowptr[dst + 1];
    const float add = ad_[dst];
    const int q = lane >> 4;          // quarter 0..3 (edge within group of 4)
    const int i16 = lane & 15;        // u32 index within 64-B row
    const int bf = flags[0];
    const u32* __restrict__ h32 = (const u32*)h;

    float m = -1e30f, l = 0.f, acc0 = 0.f, acc1 = 0.f;
    for (int base = beg; base < end; base += 64) {
        int j = base + lane;
        int sj = 0;
        float sc = -1e30f;
        if (j < end) { sj = ssrc[j]; sc = lrelu(as_[sj] + add); }
        float cm = sc;
        #pragma unroll
        for (int off = 32; off > 0; off >>= 1) cm = fmaxf(cm, __shfl_xor(cm, off));
        float nm = fmaxf(m, cm);
        float scale = __expf(m - nm);
        float ex = (j < end) ? __expf(sc - nm) : 0.f;
        float cs = ex;
        #pragma unroll
        for (int off = 32; off > 0; off >>= 1) cs += __shfl_xor(cs, off);
        l = l * scale + cs;
        acc0 *= scale; acc1 *= scale;
        m = nm;

        const int cnt = min(64, end - base);
        int jj = 0;
        for (; jj + 8 <= cnt; jj += 8) {
            #pragma unroll
            for (int k = 0; k < 8; k += 4) {
                float w0 = rl_f(ex, jj + k),     w1 = rl_f(ex, jj + k + 1);
                float w2 = rl_f(ex, jj + k + 2), w3 = rl_f(ex, jj + k + 3);
                int   s0 = rl_i(sj, jj + k),     s1 = rl_i(sj, jj + k + 1);
                int   s2 = rl_i(sj, jj + k + 2), s3 = rl_i(sj, jj + k + 3);
                float wl = (q & 1) ? w1 : w0;
                float wh = (q & 1) ? w3 : w2;
                float w  = (q & 2) ? wh : wl;
                int   sl = (q & 1) ? s1 : s0;
                int   sh = (q & 1) ? s3 : s2;
                int   s  = (q & 2) ? sh : sl;
                u32 qv = h32[(size_t)s * 16 + i16];
                acc0 = fmaf(w, __uint_as_float(qv << 16), acc0);
                acc1 = fmaf(w, __uint_as_float(qv & 0xFFFF0000u), acc1);
            }
        }
        for (; jj + 4 <= cnt; jj += 4) {
            float w0 = rl_f(ex, jj),     w1 = rl_f(ex, jj + 1);
            float w2 = rl_f(ex, jj + 2), w3 = rl_f(ex, jj + 3);
            int   s0 = rl_i(sj, jj),     s1 = rl_i(sj, jj + 1);
            int   s2 = rl_i(sj, jj + 2), s3 = rl_i(sj, jj + 3);
            float wl = (q & 1) ? w1 : w0;
            float wh = (q & 1) ? w3 : w2;
            float w  = (q & 2) ? wh : wl;
            int   sl = (q & 1) ? s1 : s0;
            int   sh = (q & 1) ? s3 : s2;
            int   s  = (q & 2) ? sh : sl;
            u32 qv = h32[(size_t)s * 16 + i16];
            acc0 = fmaf(w, __uint_as_float(qv << 16), acc0);
            acc1 = fmaf(w, __uint_as_float(qv & 0xFFFF0000u), acc1);
        }
        for (; jj < cnt; ++jj) {   // tail: one edge, only quarter 0 contributes
            float w0 = rl_f(ex, jj);
            int   s0 = rl_i(sj, jj);
            float w = (q == 0) ? w0 : 0.f;
            u32 qv = h32[(size_t)s0 * 16 + i16];
            acc0 = fmaf(w, __uint_as_float(qv << 16), acc0);
            acc1 = fmaf(w, __uint_as_float(qv & 0xFFFF0000u), acc1);
        }
    }
    acc0 += __shfl_xor(acc0, 16); acc0 += __shfl_xor(acc0, 32);
    acc1 += __shfl_xor(acc1, 16); acc1 += __shfl_xor(acc1, 32);

    // fused bias + log_softmax: 16 lanes x 2 channels (replicated across quarters)
    float inv = 1.f / l;
    float v0 = acc0 * inv + ldf(b2, 2 * i16, bf);
    float v1 = acc1 * inv + ldf(b2, 2 * i16 + 1, bf);
    float mx = fmaxf(v0, v1);
    #pragma unroll
    for (int off = 1; off < 16; off <<= 1) mx = fmaxf(mx, __shfl_xor(mx, off));
    float ss = __expf(v0 - mx) + __expf(v1 - mx);
    #pragma unroll
    for (int off = 1; off < 16; off <<= 1) ss += __shfl_xor(ss, off);
    float lg = mx + __logf(ss);
    if (lane < 16)
        *(float2*)&out[(size_t)dst * 32 + 2 * i16] = make_float2(v0 - lg, v1 - lg);
}

// ---------------------------------------------------------------------------
// GEMM2: hin = relu(agg1 + b1); h2[N,32](bf16) = hin[N,64] @ W[64,32]; alphas.
// ---------------------------------------------------------------------------
__global__ __launch_bounds__(256) void gemm2_kernel(
    const float* __restrict__ agg1, const void* __restrict__ b1,
    const u32* __restrict__ W32, const void* __restrict__ a_src,
    const void* __restrict__ a_dst, const int* __restrict__ flags,
    u16* __restrict__ h, float* __restrict__ as_, float* __restrict__ ad_)
{
    __shared__ __align__(16) float Wl[64 * 32];
    __shared__ __align__(16) float xs[64 * 68];
    const int tid = threadIdx.x;
    const int node0 = blockIdx.x * 64;
    const int bf = flags[0];

    if (bf) {
        for (int i = tid; i < 1024; i += 256) {
            u32 u = W32[i];
            *(float2*)&Wl[2 * i] = make_float2(__uint_as_float(u << 16),
                                               __uint_as_float(u & 0xFFFF0000u));
        }
    } else {
        for (int i = tid; i < 2048; i += 256) Wl[i] = __uint_as_float(W32[i]);
    }
    for (int i = tid; i < 64 * 64; i += 256) {
        int nl = i >> 6, k = i & 63;
        int n = node0 + nl;
        float v = 0.f;
        if (n < N_NODES) v = agg1[(size_t)n * 64 + k] + ldf(b1, k, bf);
        xs[nl * 68 + k] = fmaxf(v, 0.f);
    }
    __syncthreads();

    const int ch0 = (tid & 7) * 4;
    const int n0 = (tid >> 3) * 2;
    float acc0[4] = {0.f, 0.f, 0.f, 0.f}, acc1[4] = {0.f, 0.f, 0.f, 0.f};
    for (int k = 0; k < 64; k += 4) {
        float4 xa = *(const float4*)&xs[n0 * 68 + k];
        float4 xb = *(const float4*)&xs[(n0 + 1) * 68 + k];
        const float* xap = (const float*)&xa;
        const float* xbp = (const float*)&xb;
        #pragma unroll
        for (int kk = 0; kk < 4; ++kk) {
            float4 w = *(const float4*)&Wl[(k + kk) * 32 + ch0];
            float va = xap[kk], vb = xbp[kk];
            acc0[0] += va * w.x; acc0[1] += va * w.y; acc0[2] += va * w.z; acc0[3] += va * w.w;
            acc1[0] += vb * w.x; acc1[1] += vb * w.y; acc1[2] += vb * w.z; acc1[3] += vb * w.w;
        }
    }
    float ps0 = 0.f, ps1 = 0.f, pd0 = 0.f, pd1 = 0.f;
    #pragma unroll
    for (int q = 0; q < 4; ++q) {
        float asv = ldf(a_src, ch0 + q, bf);
        float adv = ldf(a_dst, ch0 + q, bf);
        ps0 += acc0[q] * asv; pd0 += acc0[q] * adv;
        ps1 += acc1[q] * asv; pd1 += acc1[q] * adv;
    }
    #pragma unroll
    for (int off = 1; off < 8; off <<= 1) {
        ps0 += __shfl_xor(ps0, off);
        pd0 += __shfl_xor(pd0, off);
        ps1 += __shfl_xor(ps1, off);
        pd1 += __shfl_xor(pd1, off);
    }
    int na = node0 + n0, nb = na + 1;
    if (na < N_NODES) {
        u32 p0 = (u32)f2bf(acc0[0]) | ((u32)f2bf(acc0[1]) << 16);
        u32 p1 = (u32)f2bf(acc0[2]) | ((u32)f2bf(acc0[3]) << 16);
        *(uint2*)&h[(size_t)na * 32 + ch0] = make_uint2(p0, p1);
        if ((tid & 7) == 0) { as_[na] = ps0; ad_[na] = pd0; }
    }
    if (nb < N_NODES) {
        u32 p0 = (u32)f2bf(acc1[0]) | ((u32)f2bf(acc1[1]) << 16);
        u32 p1 = (u32)f2bf(acc1[2]) | ((u32)f2bf(acc1[3]) << 16);
        *(uint2*)&h[(size_t)nb * 32 + ch0] = make_uint2(p0, p1);
        if ((tid & 7) == 0) { as_[nb] = ps1; ad_[nb] = pd1; }
    }
}

// ---------------------------------------------------------------------------
extern "C" void kernel_launch(void* const* d_in, const int* in_sizes, int n_in,
                              void* d_out, int out_size, void* d_ws, size_t ws_size,
                              hipStream_t stream) {
    const float* x   = (const float*)d_in[0];
    const int* ei    = (const int*)d_in[1];
    const float* W1  = (const float*)d_in[2];
    const void* a_s1 = d_in[3];
    const void* a_d1 = d_in[4];
    const void* b1   = d_in[5];
    const u32* W2    = (const u32*)d_in[6];
    const void* a_s2 = d_in[7];
    const void* a_d2 = d_in[8];
    const void* b2   = d_in[9];
    float* out = (float*)d_out;

    // workspace carve-up (~55 MB)
    char* base = (char*)d_ws;
    int* flags = (int*)base;
    u16* h     = (u16*)(base + 64);                           // N*64 bf16 (reused N*32)
    char* q = base + 64 + (size_t)N_NODES * 64 * 2;
    float* as1 = (float*)q; q += (size_t)N_NODES * 4;
    float* ad1 = (float*)q; q += (size_t)N_NODES * 4;
    float* as2 = (float*)q; q += (size_t)N_NODES * 4;
    float* ad2 = (float*)q; q += (size_t)N_NODES * 4;
    float* agg1 = (float*)q; q += (size_t)N_NODES * 64 * 4;
    u32*  bbuf  = (u32*)q;  q += (size_t)NBUCK * BCAP * 4;    // 8.03 MB
    int* rowptr = (int*)q;  q += (size_t)(N_NODES + 16) * 4;
    int* ssrc   = (int*)q;  q += (size_t)ET * 4;
    int* bcnt   = (int*)q;  q += 256 * 4;
    int* bbase  = (int*)q;  q += 256 * 4;

    detect_kernel<<<1, 64, 0, stream>>>((const u32*)x, ei, flags, bcnt);

    // CSR by dst via 2-pass bucket sort (rowptr built in scatter)
    bin_kernel<<<(ET + BINCH - 1) / BINCH, 256, 0, stream>>>(ei, flags, bcnt, bbuf);
    bscan_kernel<<<1, 256, 0, stream>>>(bcnt, bbase);
    scatter_kernel<<<NBUCK, 1024, 0, stream>>>(bcnt, bbase, bbuf, rowptr, ssrc);

    // layer 1
    gemm1_kernel<<<(N_NODES + 255) / 256, 256, 0, stream>>>(x, W1, a_s1, a_d1, flags, h, as1, ad1);
    gat_agg64_kernel<<<(N_NODES + 3) / 4, 256, 0, stream>>>(rowptr, ssrc, as1, ad1, h, agg1);

    // layer 2 (lsm fused; writes d_out directly)
    gemm2_kernel<<<(N_NODES + 63) / 64, 256, 0, stream>>>(agg1, b1, W2, a_s2, a_d2, flags, h, as2, ad2);
    gat_agg32_lsm_kernel<<<(N_NODES + 3) / 4, 256, 0, stream>>>(rowptr, ssrc, as2, ad2, h, b2, flags, out);
}